// Round 21
// baseline (284.815 us; speedup 1.0000x reference)
//
#include <hip/hip_runtime.h>
#include <math.h>

// EmbeddingEncoder: B=128, S=384, D=96, H=4, K=7, L=4.
// Round 21: round-20 with the V' layout bug fixed — conv3p now stores V' in
// 32-key-chunk-major order [b][chunk32(12)][n(6)][512] to match attn_g's
// staged reads. (r20 kept the 64-key order -> PV read scrambled V, absmax 8.9.)

constexpr int B = 128;
constexpr int S = 384;
constexpr int D = 96;
constexpr int H = 4;
constexpr int KW = 7;
constexpr int L = 4;
constexpr int ROWS = B * S;                      // 49152
constexpr long long NTOT = (long long)ROWS * D;  // 4718592
constexpr float SQRTD = 9.797958971132712f;

typedef _Float16 f16x8 __attribute__((ext_vector_type(8)));
typedef float f32x4 __attribute__((ext_vector_type(4)));
typedef unsigned short us;
typedef unsigned short us8 __attribute__((ext_vector_type(8)));

__device__ __forceinline__ us f2h(float f) {
    _Float16 h = (_Float16)f;
    return __builtin_bit_cast(us, h);
}
__device__ __forceinline__ f16x8 ldh(const us* p) {
    return *reinterpret_cast<const f16x8*>(p);
}

// ---------------- positional encoding ----------------
__global__ void pe_kernel(float* __restrict__ pe) {
    int idx = blockIdx.x * 256 + threadIdx.x;
    if (idx >= S * D) return;
    int s = idx / D, c = idx - s * D;
    int j = c >> 1;
    float expo = (c & 1) ? (4.0f * j + 2.0f) / 96.0f : (4.0f * j) / 96.0f;
    float freq = expf(-expo * logf(10000.0f));
    float ang = (float)s * freq;
    pe[idx] = (c & 1) ? cosf(ang) : sinf(ang);
}

// ---------------- weight prep (ALL weights to fragment order) ----------------
__global__ void prep_w(const float* __restrict__ WQ, const float* __restrict__ WK,
                       const float* __restrict__ cpw, const float* __restrict__ w1,
                       const float* __restrict__ w2,
                       us* __restrict__ wqS, us* __restrict__ wkS, us* __restrict__ pwS,
                       us* __restrict__ w1S, us* __restrict__ w2S) {
    int idx = blockIdx.x * 256 + threadIdx.x;
    if (idx >= H * D * D) return;  // 36864
    int h = idx / (D * D), rem = idx - h * (D * D);
    int d = rem / D, e = rem - d * D;
    int n = e >> 4, lmod = e & 15, kk = d >> 5, ldiv = (d >> 3) & 3, j = d & 7;
    size_t fi = (size_t)(((n * 3 + kk) * 64 + ldiv * 16 + lmod) * 8 + j);
    wqS[(size_t)h * D * D + fi] = f2h(WQ[idx] * SQRTD);
    wkS[(size_t)h * D * D + fi] = f2h(WK[idx]);
    {
        int l = idx / (D * D);
        int o = rem / D, c = rem - o * D;
        int no = o >> 4, lo = o & 15, kc = c >> 5, lc = (c >> 3) & 3, jc = c & 7;
        pwS[(size_t)l * D * D + (size_t)(((no * 3 + kc) * 64 + lc * 16 + lo) * 8 + jc)] =
            f2h(cpw[idx]);
    }
    if (idx < 48 * 96) {
        int m = idx / 96, c = idx - m * 96;
        int nm = m >> 4, lm = m & 15, kc = c >> 5, lc = (c >> 3) & 3, jc = c & 7;
        w1S[((nm * 3 + kc) * 64 + lc * 16 + lm) * 8 + jc] = f2h(w1[c * 48 + m]);
    }
    if (idx < 96 * 64) {
        int o = idx / 64, mk = idx - o * 64;
        int no = o >> 4, lo = o & 15, km = mk >> 5, lm2 = (mk >> 3) & 3, jm = mk & 7;
        w2S[((no * 2 + km) * 64 + lm2 * 16 + lo) * 8 + jm] =
            (mk < 48) ? f2h(w2[mk * 96 + o]) : (us)0;
    }
}

// ---------------- WVO_h = WV_h @ WO_h -> fragment order ----------------
__global__ void prep_wvo(const float* __restrict__ WV, const float* __restrict__ WO,
                         us* __restrict__ wvoS) {
    int blk = blockIdx.x;  // 24 = H * 6
    int h = blk / 6, ot = blk - h * 6;
    int tid = threadIdx.x;
    const float* wv = WV + (size_t)h * D * D;
    const float* wo = WO + (size_t)h * D * D;
    for (int i = tid; i < 16 * 96; i += 256) {
        int lmod = i / 96, d = i - (i / 96) * 96;
        int o = ot * 16 + lmod;
        float acc = 0.f;
        for (int e = 0; e < 96; e++) acc += wv[d * 96 + e] * wo[e * 96 + o];
        int kk = d >> 5, ldiv = (d >> 3) & 3, j = d & 7;
        wvoS[(size_t)h * D * D + (size_t)(((ot * 3 + kk) * 64 + ldiv * 16 + lmod) * 8 + j)] =
            f2h(acc);
    }
}

// ---------------- conv0: embed + LN0 (halo inline) + dw + pw + residual + LN1 ----------------
__global__ void conv0f(const float* __restrict__ in, const float* __restrict__ pe,
                       const float* __restrict__ g0, const float* __restrict__ b0,
                       float* __restrict__ xout, us* __restrict__ lnout,
                       const float* __restrict__ dwW, const float* __restrict__ dwB,
                       const us* __restrict__ pwW, const float* __restrict__ pwb,
                       const float* __restrict__ gnext, const float* __restrict__ bnext) {
    __shared__ us lnb_s[70 * 104];
    __shared__ us dwb_s[64 * 104];
    __shared__ float lw[96 * 8];
    int tid = threadIdx.x;
    int wave = tid >> 6, lane = tid & 63;
    int r0 = blockIdx.x * 64;
    int b = r0 / S, s0 = r0 % S;

    for (int i = tid; i < 96 * KW; i += 256) lw[(i / KW) * 8 + (i % KW)] = dwW[i];

    for (int i = wave; i < 70; i += 4) {
        int s = s0 - 3 + i;
        bool valid = (unsigned)s < (unsigned)S;
        float v0 = 0.f, v1 = 0.f;
        if (valid) {
            size_t ro = ((size_t)b * S + s) * 96;
            v0 = in[ro + lane] * SQRTD + pe[s * 96 + lane];
            v1 = (lane < 32) ? in[ro + 64 + lane] * SQRTD + pe[s * 96 + 64 + lane] : 0.f;
        }
        float sm = v0 + v1, q = v0 * v0 + v1 * v1;
        for (int off = 32; off > 0; off >>= 1) {
            sm += __shfl_xor(sm, off);
            q += __shfl_xor(q, off);
        }
        float mean = sm * (1.0f / D);
        float var = q * (1.0f / D) - mean * mean;
        float rstd = rsqrtf(var + 1e-5f);
        lnb_s[i * 104 + lane] = f2h(valid ? (v0 - mean) * rstd * g0[lane] + b0[lane] : 0.f);
        if (lane < 32)
            lnb_s[i * 104 + 64 + lane] =
                f2h(valid ? (v1 - mean) * rstd * g0[lane + 64] + b0[lane + 64] : 0.f);
    }
    __syncthreads();

    for (int u = tid; u < 768; u += 256) {
        int j = u / 12, c0 = (u - (u / 12) * 12) * 8;
        float acc[8];
        #pragma unroll
        for (int j2 = 0; j2 < 8; j2++) acc[j2] = dwB[c0 + j2];
        #pragma unroll
        for (int k = 0; k < KW; k++) {
            f16x8 v = ldh(&lnb_s[(j + k) * 104 + c0]);
            #pragma unroll
            for (int j2 = 0; j2 < 8; j2++) acc[j2] += (float)v[j2] * lw[(c0 + j2) * 8 + k];
        }
        us8 o;
        #pragma unroll
        for (int j2 = 0; j2 < 8; j2++) o[j2] = f2h(acc[j2]);
        *reinterpret_cast<us8*>(&dwb_s[j * 104 + c0]) = o;
    }
    __syncthreads();

    int lmod = lane & 15, ldiv = lane >> 4, m0 = wave * 16;
    f32x4 acc[6] = {};
    #pragma unroll
    for (int kk = 0; kk < 3; kk++) {
        f16x8 af = ldh(&dwb_s[(m0 + lmod) * 104 + kk * 32 + ldiv * 8]);
        #pragma unroll
        for (int n = 0; n < 6; n++) {
            f16x8 bf = ldh(pwW + (size_t)((n * 3 + kk) * 64) * 8 + lane * 8);
            acc[n] = __builtin_amdgcn_mfma_f32_16x16x32_f16(af, bf, acc[n], 0, 0, 0);
        }
    }

    float gv[6], bv2[6], pb[6];
    #pragma unroll
    for (int n = 0; n < 6; n++) {
        int o = n * 16 + lmod;
        gv[n] = gnext[o];
        bv2[n] = bnext[o];
        pb[n] = pwb[o];
    }
    #pragma unroll
    for (int n = 0; n < 6; n++) {
        int o = n * 16 + lmod;
        #pragma unroll
        for (int r = 0; r < 4; r++) {
            int sr = m0 + ldiv * 4 + r;
            size_t row = (size_t)r0 + sr;
            float base = in[row * 96 + o] * SQRTD + pe[(s0 + sr) * 96 + o];
            acc[n][r] = base + fmaxf(acc[n][r] + pb[n], 0.f);
        }
    }
    #pragma unroll
    for (int r = 0; r < 4; r++) {
        float sm = 0.f, qq = 0.f;
        #pragma unroll
        for (int n = 0; n < 6; n++) {
            sm += acc[n][r];
            qq += acc[n][r] * acc[n][r];
        }
        #pragma unroll
        for (int st = 1; st <= 8; st <<= 1) {
            sm += __shfl_xor(sm, st);
            qq += __shfl_xor(qq, st);
        }
        float mean = sm * (1.0f / D);
        float var = qq * (1.0f / D) - mean * mean;
        float rstd = rsqrtf(var + 1e-5f);
        size_t row = (size_t)r0 + m0 + ldiv * 4 + r;
        #pragma unroll
        for (int n = 0; n < 6; n++) {
            int o = n * 16 + lmod;
            xout[row * 96 + o] = acc[n][r];
            lnout[row * 96 + o] = f2h((acc[n][r] - mean) * rstd * gv[n] + bv2[n]);
        }
    }
}

// ---------------- mid conv layer ----------------
__global__ void conv2(const float* __restrict__ xin, const us* __restrict__ lnin,
                      float* __restrict__ xout, us* __restrict__ lnout,
                      const float* __restrict__ dwW, const float* __restrict__ dwB,
                      const us* __restrict__ pwW, const float* __restrict__ pwb,
                      const float* __restrict__ gnext, const float* __restrict__ bnext) {
    __shared__ us dwb_s[64 * 104];
    __shared__ float lw[96 * 8];
    int tid = threadIdx.x;
    int wave = tid >> 6, lane = tid & 63;
    int r0 = blockIdx.x * 64;
    int b = r0 / S, s0 = r0 % S;

    for (int i = tid; i < 96 * KW; i += 256) lw[(i / KW) * 8 + (i % KW)] = dwW[i];
    __syncthreads();

    for (int u = tid; u < 768; u += 256) {
        int j = u / 12, c0 = (u - (u / 12) * 12) * 8;
        float acc[8];
        #pragma unroll
        for (int j2 = 0; j2 < 8; j2++) acc[j2] = dwB[c0 + j2];
        #pragma unroll
        for (int k = 0; k < KW; k++) {
            int ss = s0 + j + k - 3;
            if ((unsigned)ss < (unsigned)S) {
                f16x8 v = ldh(lnin + ((size_t)b * S + ss) * 96 + c0);
                #pragma unroll
                for (int j2 = 0; j2 < 8; j2++) acc[j2] += (float)v[j2] * lw[(c0 + j2) * 8 + k];
            }
        }
        us8 o;
        #pragma unroll
        for (int j2 = 0; j2 < 8; j2++) o[j2] = f2h(acc[j2]);
        *reinterpret_cast<us8*>(&dwb_s[j * 104 + c0]) = o;
    }
    __syncthreads();

    int lmod = lane & 15, ldiv = lane >> 4, m0 = wave * 16;
    f32x4 acc[6] = {};
    #pragma unroll
    for (int kk = 0; kk < 3; kk++) {
        f16x8 af = ldh(&dwb_s[(m0 + lmod) * 104 + kk * 32 + ldiv * 8]);
        #pragma unroll
        for (int n = 0; n < 6; n++) {
            f16x8 bf = ldh(pwW + (size_t)((n * 3 + kk) * 64) * 8 + lane * 8);
            acc[n] = __builtin_amdgcn_mfma_f32_16x16x32_f16(af, bf, acc[n], 0, 0, 0);
        }
    }

    float gv[6], bv2[6], pb[6];
    #pragma unroll
    for (int n = 0; n < 6; n++) {
        int o = n * 16 + lmod;
        gv[n] = gnext[o];
        bv2[n] = bnext[o];
        pb[n] = pwb[o];
    }
    #pragma unroll
    for (int n = 0; n < 6; n++) {
        #pragma unroll
        for (int r = 0; r < 4; r++) {
            size_t row = (size_t)r0 + m0 + ldiv * 4 + r;
            acc[n][r] = xin[row * 96 + n * 16 + lmod] + fmaxf(acc[n][r] + pb[n], 0.f);
        }
    }
    #pragma unroll
    for (int r = 0; r < 4; r++) {
        float sm = 0.f, qq = 0.f;
        #pragma unroll
        for (int n = 0; n < 6; n++) {
            sm += acc[n][r];
            qq += acc[n][r] * acc[n][r];
        }
        #pragma unroll
        for (int st = 1; st <= 8; st <<= 1) {
            sm += __shfl_xor(sm, st);
            qq += __shfl_xor(qq, st);
        }
        float mean = sm * (1.0f / D);
        float var = qq * (1.0f / D) - mean * mean;
        float rstd = rsqrtf(var + 1e-5f);
        size_t row = (size_t)r0 + m0 + ldiv * 4 + r;
        #pragma unroll
        for (int n = 0; n < 6; n++) {
            int o = n * 16 + lmod;
            xout[row * 96 + o] = acc[n][r];
            lnout[row * 96 + o] = f2h((acc[n][r] - mean) * rstd * gv[n] + bv2[n]);
        }
    }
}

// ---------------- conv3 + K/V' projection fused (V 32-key-chunk-major) ----------------
__global__ void conv3p(const float* __restrict__ xin, const us* __restrict__ lnin,
                       float* __restrict__ xout, us* __restrict__ lnout,
                       const float* __restrict__ dwW, const float* __restrict__ dwB,
                       const us* __restrict__ pwW, const float* __restrict__ pwb,
                       const float* __restrict__ gnext, const float* __restrict__ bnext,
                       const us* __restrict__ wkS, const us* __restrict__ wvoS,
                       us* __restrict__ Kall, us* __restrict__ Vall) {
    __shared__ float lw[96 * 8];
    __shared__ us stg[96 * 72];
    __shared__ us lnstg[64 * 104];
    int tid = threadIdx.x;
    int wave = tid >> 6, lane = tid & 63;
    int lmod = lane & 15, ldiv = lane >> 4, m0 = wave * 16;
    int r0 = blockIdx.x * 64;
    int b = r0 / S, s0 = r0 % S;

    for (int i = tid; i < 96 * KW; i += 256) lw[(i / KW) * 8 + (i % KW)] = dwW[i];
    __syncthreads();

    for (int u = tid; u < 768; u += 256) {
        int j = u / 12, c0 = (u - (u / 12) * 12) * 8;
        float acc[8];
        #pragma unroll
        for (int j2 = 0; j2 < 8; j2++) acc[j2] = dwB[c0 + j2];
        #pragma unroll
        for (int k = 0; k < KW; k++) {
            int ss = s0 + j + k - 3;
            if ((unsigned)ss < (unsigned)S) {
                f16x8 v = ldh(lnin + ((size_t)b * S + ss) * 96 + c0);
                #pragma unroll
                for (int j2 = 0; j2 < 8; j2++) acc[j2] += (float)v[j2] * lw[(c0 + j2) * 8 + k];
            }
        }
        us8 o;
        #pragma unroll
        for (int j2 = 0; j2 < 8; j2++) o[j2] = f2h(acc[j2]);
        *reinterpret_cast<us8*>(&stg[j * 104 + c0]) = o;
    }
    __syncthreads();

    f32x4 acc[6] = {};
    #pragma unroll
    for (int kk = 0; kk < 3; kk++) {
        f16x8 af = ldh(&stg[(m0 + lmod) * 104 + kk * 32 + ldiv * 8]);
        #pragma unroll
        for (int n = 0; n < 6; n++) {
            f16x8 bf = ldh(pwW + (size_t)((n * 3 + kk) * 64) * 8 + lane * 8);
            acc[n] = __builtin_amdgcn_mfma_f32_16x16x32_f16(af, bf, acc[n], 0, 0, 0);
        }
    }

    float gv[6], bv2[6], pb[6];
    #pragma unroll
    for (int n = 0; n < 6; n++) {
        int o = n * 16 + lmod;
        gv[n] = gnext[o];
        bv2[n] = bnext[o];
        pb[n] = pwb[o];
    }
    #pragma unroll
    for (int n = 0; n < 6; n++) {
        #pragma unroll
        for (int r = 0; r < 4; r++) {
            size_t row = (size_t)r0 + m0 + ldiv * 4 + r;
            acc[n][r] = xin[row * 96 + n * 16 + lmod] + fmaxf(acc[n][r] + pb[n], 0.f);
        }
    }
    #pragma unroll
    for (int r = 0; r < 4; r++) {
        float sm = 0.f, qq = 0.f;
        #pragma unroll
        for (int n = 0; n < 6; n++) {
            sm += acc[n][r];
            qq += acc[n][r] * acc[n][r];
        }
        #pragma unroll
        for (int st = 1; st <= 8; st <<= 1) {
            sm += __shfl_xor(sm, st);
            qq += __shfl_xor(qq, st);
        }
        float mean = sm * (1.0f / D);
        float var = qq * (1.0f / D) - mean * mean;
        float rstd = rsqrtf(var + 1e-5f);
        size_t row = (size_t)r0 + m0 + ldiv * 4 + r;
        #pragma unroll
        for (int n = 0; n < 6; n++) {
            int o = n * 16 + lmod;
            xout[row * 96 + o] = acc[n][r];
            us hv = f2h((acc[n][r] - mean) * rstd * gv[n] + bv2[n]);
            lnout[row * 96 + o] = hv;
            lnstg[(m0 + ldiv * 4 + r) * 104 + o] = hv;
        }
    }
    __syncthreads();

    f16x8 af[3];
    #pragma unroll
    for (int kk = 0; kk < 3; kk++)
        af[kk] = ldh(&lnstg[(m0 + lmod) * 104 + kk * 32 + ldiv * 8]);

    for (int hd = 0; hd < H; hd++) {
        // ---- K ----
        f32x4 ka[6] = {};
        #pragma unroll
        for (int kk = 0; kk < 3; kk++)
            #pragma unroll
            for (int n = 0; n < 6; n++) {
                f16x8 bf = ldh(wkS + (size_t)hd * D * D + (size_t)((n * 3 + kk) * 64) * 8 + lane * 8);
                ka[n] = __builtin_amdgcn_mfma_f32_16x16x32_f16(af[kk], bf, ka[n], 0, 0, 0);
            }
        __syncthreads();
        us* kT = stg + wave * 1664;
        #pragma unroll
        for (int n = 0; n < 6; n++)
            #pragma unroll
            for (int r = 0; r < 4; r++)
                kT[(ldiv * 4 + r) * 104 + n * 16 + lmod] = f2h(ka[n][r]);
        int t0 = (r0 % S) / 16 + wave;
        us* dst = Kall + (size_t)hd * NTOT + ((size_t)(b * 24 + t0) * 3) * 512;
        #pragma unroll
        for (int kk = 0; kk < 3; kk++) {
            us8 v = *reinterpret_cast<const us8*>(&kT[lmod * 104 + kk * 32 + ldiv * 8]);
            *reinterpret_cast<us8*>(dst + kk * 512 + lane * 8) = v;
        }
        // ---- V' ---- 32-key-chunk-major: [b][chunk32 = cblk*2+kk][n][512]
        f32x4 va[6] = {};
        #pragma unroll
        for (int kk = 0; kk < 3; kk++)
            #pragma unroll
            for (int n = 0; n < 6; n++) {
                f16x8 bf =
                    ldh(wvoS + (size_t)hd * D * D + (size_t)((n * 3 + kk) * 64) * 8 + lane * 8);
                va[n] = __builtin_amdgcn_mfma_f32_16x16x32_f16(af[kk], bf, va[n], 0, 0, 0);
            }
        __syncthreads();
        #pragma unroll
        for (int n = 0; n < 6; n++)
            #pragma unroll
            for (int r = 0; r < 4; r++)
                stg[(n * 16 + lmod) * 72 + m0 + ldiv * 4 + r] = f2h(va[n][r]);
        __syncthreads();
        int cblk = (r0 % S) / 64;
        us* dsth = Vall + (size_t)hd * NTOT;
        #pragma unroll
        for (int n = 0; n < 6; n++)
            #pragma unroll
            for (int kk = 0; kk < 2; kk++) {
                us8 v =
                    *reinterpret_cast<const us8*>(&stg[(n * 16 + lmod) * 72 + kk * 32 + ldiv * 8]);
                *reinterpret_cast<us8*>(
                    dsth + ((size_t)((b * 12 + cblk * 2 + kk) * 6 + n)) * 512 + lane * 8) = v;
            }
    }
}

// ---------------- block-cooperative LDS-staged attention, 32-key chunks ----------------
// grid 1536 = 128 b x 4 hd x 3 qthird; 4 waves x 32 q-rows; LDS pool 34.8 KB.
__global__ __launch_bounds__(256, 2) void attn_g(const us* __restrict__ h16,
                                                 const us* __restrict__ wqS,
                                                 const us* __restrict__ Kall,
                                                 const us* __restrict__ Vall,
                                                 us* __restrict__ xpart) {
    __shared__ us pool[17408];  // Kb: 0/3072 | Vb: 6144/9216 | P: 12288 + wave*1280
    int tid = threadIdx.x, wave = tid >> 6, lane = tid & 63;
    int lmod = lane & 15, ldiv = lane >> 4;
    int p = blockIdx.x;
    int gl = (p & 7) * 192 + (p >> 3);  // XCD swizzle, 1536 = 8*192
    int qt = gl % 3;
    int bh = gl / 3;
    int b = bh >> 2, hd = bh & 3;
    size_t rowbase = (size_t)b * S + qt * 128 + wave * 32;

    const us* Kh = Kall + (size_t)hd * NTOT + (size_t)b * 24 * 1536;
    const us* Vh = Vall + (size_t)hd * NTOT + (size_t)b * 36 * 1024;
    us* P = pool + 12288 + wave * 1280;  // [32][40]
    bool has1 = tid < 128;

    us8 k00, k01;
    k00 = *reinterpret_cast<const us8*>(Kh + (size_t)tid * 8);
    if (has1) k01 = *reinterpret_cast<const us8*>(Kh + (size_t)(256 + tid) * 8);

    f32x4 qa0[6] = {}, qa1[6] = {};
    #pragma unroll
    for (int kk = 0; kk < 3; kk++) {
        f16x8 a0 = ldh(h16 + (rowbase + lmod) * 96 + kk * 32 + ldiv * 8);
        f16x8 a1 = ldh(h16 + (rowbase + 16 + lmod) * 96 + kk * 32 + ldiv * 8);
        #pragma unroll
        for (int n = 0; n < 6; n++) {
            f16x8 bf = ldh(wqS + (size_t)hd * D * D + (size_t)((n * 3 + kk) * 64) * 8 + lane * 8);
            qa0[n] = __builtin_amdgcn_mfma_f32_16x16x32_f16(a0, bf, qa0[n], 0, 0, 0);
            qa1[n] = __builtin_amdgcn_mfma_f32_16x16x32_f16(a1, bf, qa1[n], 0, 0, 0);
        }
    }
    us* qst = pool + wave * 3328;  // [32][104], wave-private
    #pragma unroll
    for (int n = 0; n < 6; n++)
        #pragma unroll
        for (int r = 0; r < 4; r++) {
            qst[(ldiv * 4 + r) * 104 + n * 16 + lmod] = f2h(qa0[n][r]);
            qst[(16 + ldiv * 4 + r) * 104 + n * 16 + lmod] = f2h(qa1[n][r]);
        }
    f16x8 aq0[3], aq1[3];
    #pragma unroll
    for (int kk = 0; kk < 3; kk++) {
        aq0[kk] = ldh(&qst[lmod * 104 + kk * 32 + ldiv * 8]);
        aq1[kk] = ldh(&qst[(16 + lmod) * 104 + kk * 32 + ldiv * 8]);
    }
    __syncthreads();  // all waves done reading Q slices from pool
    *reinterpret_cast<us8*>(&pool[tid * 8]) = k00;
    if (has1) *reinterpret_cast<us8*>(&pool[(256 + tid) * 8]) = k01;
    __syncthreads();

    // ---- pass 1: row max (12 chunks of 32 keys) ----
    f32x4 mx0 = {-1e30f, -1e30f, -1e30f, -1e30f}, mx1 = mx0;
    for (int c = 0; c < 12; c++) {
        us* kbc = pool + (c & 1) * 3072;
        us8 kn0, kn1, vn0, vn1;
        bool last = (c == 11);
        if (!last) {
            const us* src = Kh + (size_t)(c + 1) * 3072;
            kn0 = *reinterpret_cast<const us8*>(src + (size_t)tid * 8);
            if (has1) kn1 = *reinterpret_cast<const us8*>(src + (size_t)(256 + tid) * 8);
        } else {
            kn0 = *reinterpret_cast<const us8*>(Kh + (size_t)tid * 8);
            if (has1) kn1 = *reinterpret_cast<const us8*>(Kh + (size_t)(256 + tid) * 8);
            vn0 = *reinterpret_cast<const us8*>(Vh + (size_t)tid * 8);
            if (has1) vn1 = *reinterpret_cast<const us8*>(Vh + (size_t)(256 + tid) * 8);
        }
        __builtin_amdgcn_s_setprio(1);
        f32x4 s0[2] = {}, s1[2] = {};
        #pragma unroll
        for (int nt = 0; nt < 2; nt++)
            #pragma unroll
            for (int kk = 0; kk < 3; kk++) {
                f16x8 bf = ldh(&kbc[(nt * 3 + kk) * 512 + lane * 8]);
                s0[nt] = __builtin_amdgcn_mfma_f32_16x16x32_f16(aq0[kk], bf, s0[nt], 0, 0, 0);
                s1[nt] = __builtin_amdgcn_mfma_f32_16x16x32_f16(aq1[kk], bf, s1[nt], 0, 0, 0);
            }
        __builtin_amdgcn_s_setprio(0);
        #pragma unroll
        for (int nt = 0; nt < 2; nt++)
            #pragma unroll
            for (int r = 0; r < 4; r++) {
                mx0[r] = fmaxf(mx0[r], s0[nt][r]);
                mx1[r] = fmaxf(mx1[r], s1[nt][r]);
            }
        us* kbw = pool + (last ? 0 : ((c & 1) ^ 1)) * 3072;
        *reinterpret_cast<us8*>(&kbw[tid * 8]) = kn0;
        if (has1) *reinterpret_cast<us8*>(&kbw[(256 + tid) * 8]) = kn1;
        if (last) {
            *reinterpret_cast<us8*>(&pool[6144 + tid * 8]) = vn0;
            if (has1) *reinterpret_cast<us8*>(&pool[6144 + (256 + tid) * 8]) = vn1;
        }
        __syncthreads();
    }
    #pragma unroll
    for (int st = 1; st <= 8; st <<= 1)
        #pragma unroll
        for (int r = 0; r < 4; r++) {
            mx0[r] = fmaxf(mx0[r], __shfl_xor(mx0[r], st));
            mx1[r] = fmaxf(mx1[r], __shfl_xor(mx1[r], st));
        }

    // ---- pass 2: scores -> exp -> PV ----
    f32x4 oacc0[6] = {}, oacc1[6] = {};
    f32x4 l0v = {}, l1v = {};
    for (int c = 0; c < 12; c++) {
        us* kbc = pool + (c & 1) * 3072;
        us* vbc = pool + 6144 + (c & 1) * 3072;
        us8 kn0, kn1, vn0, vn1;
        if (c < 11) {
            const us* ksrc = Kh + (size_t)(c + 1) * 3072;
            const us* vsrc = Vh + (size_t)(c + 1) * 3072;
            kn0 = *reinterpret_cast<const us8*>(ksrc + (size_t)tid * 8);
            vn0 = *reinterpret_cast<const us8*>(vsrc + (size_t)tid * 8);
            if (has1) {
                kn1 = *reinterpret_cast<const us8*>(ksrc + (size_t)(256 + tid) * 8);
                vn1 = *reinterpret_cast<const us8*>(vsrc + (size_t)(256 + tid) * 8);
            }
        }
        __builtin_amdgcn_s_setprio(1);
        f32x4 s0[2] = {}, s1[2] = {};
        #pragma unroll
        for (int nt = 0; nt < 2; nt++)
            #pragma unroll
            for (int kk = 0; kk < 3; kk++) {
                f16x8 bf = ldh(&kbc[(nt * 3 + kk) * 512 + lane * 8]);
                s0[nt] = __builtin_amdgcn_mfma_f32_16x16x32_f16(aq0[kk], bf, s0[nt], 0, 0, 0);
                s1[nt] = __builtin_amdgcn_mfma_f32_16x16x32_f16(aq1[kk], bf, s1[nt], 0, 0, 0);
            }
        __builtin_amdgcn_s_setprio(0);
        #pragma unroll
        for (int nt = 0; nt < 2; nt++)
            #pragma unroll
            for (int r = 0; r < 4; r++) {
                float p0 = __expf(s0[nt][r] - mx0[r]);
                float p1 = __expf(s1[nt][r] - mx1[r]);
                l0v[r] += p0;
                l1v[r] += p1;
                P[(ldiv * 4 + r) * 40 + nt * 16 + lmod] = f2h(p0);
                P[(16 + ldiv * 4 + r) * 40 + nt * 16 + lmod] = f2h(p1);
            }
        __builtin_amdgcn_s_setprio(1);
        {
            f16x8 pf0 = ldh(&P[lmod * 40 + ldiv * 8]);
            f16x8 pf1 = ldh(&P[(16 + lmod) * 40 + ldiv * 8]);
            #pragma unroll
            for (int n = 0; n < 6; n++) {
                f16x8 bf = ldh(&vbc[n * 512 + lane * 8]);
                oacc0[n] = __builtin_amdgcn_mfma_f32_16x16x32_f16(pf0, bf, oacc0[n], 0, 0, 0);
                oacc1[n] = __builtin_amdgcn_mfma_f32_16x16x32_f16(pf1, bf, oacc1[n], 0, 0, 0);
            }
        }
        __builtin_amdgcn_s_setprio(0);
        if (c < 11) {
            us* kbn = pool + ((c & 1) ^ 1) * 3072;
            us* vbn = pool + 6144 + ((c & 1) ^ 1) * 3072;
            *reinterpret_cast<us8*>(&kbn[tid * 8]) = kn0;
            *reinterpret_cast<us8*>(&vbn[tid * 8]) = vn0;
            if (has1) {
                *reinterpret_cast<us8*>(&kbn[(256 + tid) * 8]) = kn1;
                *reinterpret_cast<us8*>(&vbn[(256 + tid) * 8]) = vn1;
            }
            __syncthreads();
        }
    }
    #pragma unroll
    for (int st = 1; st <= 8; st <<= 1)
        #pragma unroll
        for (int r = 0; r < 4; r++) {
            l0v[r] += __shfl_xor(l0v[r], st);
            l1v[r] += __shfl_xor(l1v[r], st);
        }

    us* xp = xpart + (size_t)hd * NTOT;
    #pragma unroll
    for (int r = 0; r < 4; r++) {
        float inv0 = 1.f / l0v[r];
        float inv1 = 1.f / l1v[r];
        #pragma unroll
        for (int n = 0; n < 6; n++) {
            xp[(rowbase + ldiv * 4 + r) * 96 + n * 16 + lmod] = f2h(oacc0[n][r] * inv0);
            xp[(rowbase + 16 + ldiv * 4 + r) * 96 + n * 16 + lmod] = f2h(oacc1[n][r] * inv1);
        }
    }
}

// ---------------- fused head-reduce + LN + FFN ----------------
__global__ void ffn_ln(const float* __restrict__ x, const us* __restrict__ xpart,
                       const float* __restrict__ gln, const float* __restrict__ bln,
                       const us* __restrict__ w1S, const float* __restrict__ b1,
                       const us* __restrict__ w2S, const float* __restrict__ b2,
                       float* __restrict__ out) {
    __shared__ float xf[64 * 96];
    __shared__ us lnb[64 * 104];
    __shared__ us mid[64 * 72];
    int tid = threadIdx.x, wave = tid >> 6, lane = tid & 63;
    int lmod = lane & 15, ldiv = lane >> 4, m0 = wave * 16;
    int row0 = blockIdx.x * 64;

    for (int i = wave; i < 64; i += 4) {
        size_t ro = (size_t)(row0 + i) * 96;
        float v0 = x[ro + lane];
        float v1 = (lane < 32) ? x[ro + 64 + lane] : 0.f;
        #pragma unroll
        for (int h = 0; h < H; h++) {
            const us* xp = xpart + (size_t)h * NTOT + ro;
            v0 += (float)__builtin_bit_cast(_Float16, xp[lane]);
            if (lane < 32) v1 += (float)__builtin_bit_cast(_Float16, xp[64 + lane]);
        }
        xf[i * 96 + lane] = v0;
        if (lane < 32) xf[i * 96 + 64 + lane] = v1;
        float sm = v0 + v1, q = v0 * v0 + v1 * v1;
        for (int off = 32; off > 0; off >>= 1) {
            sm += __shfl_xor(sm, off);
            q += __shfl_xor(q, off);
        }
        float mean = sm * (1.0f / D);
        float var = q * (1.0f / D) - mean * mean;
        float rstd = rsqrtf(var + 1e-5f);
        lnb[i * 104 + lane] = f2h((v0 - mean) * rstd * gln[lane] + bln[lane]);
        if (lane < 32)
            lnb[i * 104 + 64 + lane] = f2h((v1 - mean) * rstd * gln[lane + 64] + bln[lane + 64]);
    }
    __syncthreads();

    f32x4 a3[3] = {};
    #pragma unroll
    for (int kk = 0; kk < 3; kk++) {
        f16x8 af = ldh(&lnb[(m0 + lmod) * 104 + kk * 32 + ldiv * 8]);
        #pragma unroll
        for (int n = 0; n < 3; n++) {
            f16x8 bf = ldh(w1S + (size_t)((n * 3 + kk) * 64) * 8 + lane * 8);
            a3[n] = __builtin_amdgcn_mfma_f32_16x16x32_f16(af, bf, a3[n], 0, 0, 0);
        }
    }
    #pragma unroll
    for (int n = 0; n < 3; n++) {
        float bv = b1[n * 16 + lmod];
        #pragma unroll
        for (int r = 0; r < 4; r++) {
            float v = a3[n][r] + bv;
            mid[(m0 + ldiv * 4 + r) * 72 + n * 16 + lmod] = f2h(1.f / (1.f + __expf(-v)));
        }
    }
    #pragma unroll
    for (int r = 0; r < 4; r++) mid[(m0 + ldiv * 4 + r) * 72 + 48 + lmod] = 0;
    __syncthreads();

    f32x4 a6[6] = {};
    #pragma unroll
    for (int kk = 0; kk < 2; kk++) {
        f16x8 af = ldh(&mid[(m0 + lmod) * 72 + kk * 32 + ldiv * 8]);
        #pragma unroll
        for (int n = 0; n < 6; n++) {
            f16x8 bf = ldh(w2S + (size_t)((n * 2 + kk) * 64) * 8 + lane * 8);
            a6[n] = __builtin_amdgcn_mfma_f32_16x16x32_f16(af, bf, a6[n], 0, 0, 0);
        }
    }
    #pragma unroll
    for (int n = 0; n < 6; n++) {
        int o = n * 16 + lmod;
        float bv = b2[o];
        #pragma unroll
        for (int r = 0; r < 4; r++) {
            int sr = m0 + ldiv * 4 + r;
            out[(size_t)(row0 + sr) * 96 + o] = xf[sr * 96 + o] + a6[n][r] + bv;
        }
    }
}

extern "C" void kernel_launch(void* const* d_in, const int* in_sizes, int n_in,
                              void* d_out, int out_size, void* d_ws, size_t ws_size,
                              hipStream_t stream) {
    const float* in   = (const float*)d_in[0];
    const float* cdw  = (const float*)d_in[2];
    const float* cdwb = (const float*)d_in[3];
    const float* cpw  = (const float*)d_in[4];
    const float* cpwb = (const float*)d_in[5];
    const float* WQ   = (const float*)d_in[6];
    const float* WK   = (const float*)d_in[7];
    const float* WV   = (const float*)d_in[8];
    const float* WO   = (const float*)d_in[9];
    const float* w1   = (const float*)d_in[10];
    const float* b1   = (const float*)d_in[11];
    const float* w2   = (const float*)d_in[12];
    const float* b2   = (const float*)d_in[13];
    const float* lng  = (const float*)d_in[14];
    const float* lnb  = (const float*)d_in[15];
    float* out = (float*)d_out;
    float* ws = (float*)d_ws;

    float* xA  = ws;
    float* xB  = xA + NTOT;
    float* pe  = xB + NTOT;
    us* lnA    = (us*)(pe + S * D);
    us* lnB    = lnA + NTOT;
    us* Kall   = lnB + NTOT;               // [H][B][24][3][64][8]
    us* Vall   = Kall + (size_t)H * NTOT;  // [H][B][12 chunk32][6 n][512]
    us* xpart  = Vall + (size_t)H * NTOT;  // [H][ROWS][96]
    us* wqS    = xpart + (size_t)H * NTOT;
    us* wkS    = wqS + H * D * D;
    us* wvoS   = wkS + H * D * D;
    us* pwS    = wvoS + H * D * D;
    us* w1S    = pwS + L * D * D;
    us* w2S    = w1S + 48 * 96;
    // total ~= 170 MB (< 256 MB ws)

    pe_kernel<<<(S * D + 255) / 256, 256, 0, stream>>>(pe);
    prep_w<<<(H * D * D + 255) / 256, 256, 0, stream>>>(WQ, WK, cpw, w1, w2,
                                                        wqS, wkS, pwS, w1S, w2S);
    prep_wvo<<<H * 6, 256, 0, stream>>>(WV, WO, wvoS);

    conv0f<<<ROWS / 64, 256, 0, stream>>>(in, pe, lng, lnb, xA, lnB,
                                          cdw, cdwb, pwS, cpwb, lng + D, lnb + D);
    conv2<<<ROWS / 64, 256, 0, stream>>>(xA, lnB, xB, lnA, cdw + D * KW, cdwb + D,
                                         pwS + D * D, cpwb + D, lng + 2 * D, lnb + 2 * D);
    conv2<<<ROWS / 64, 256, 0, stream>>>(xB, lnA, xA, lnB, cdw + 2 * D * KW, cdwb + 2 * D,
                                         pwS + 2 * D * D, cpwb + 2 * D, lng + 3 * D,
                                         lnb + 3 * D);
    conv3p<<<ROWS / 64, 256, 0, stream>>>(xA, lnB, xB, lnA, cdw + 3 * D * KW, cdwb + 3 * D,
                                          pwS + 3 * D * D, cpwb + 3 * D, lng + 4 * D,
                                          lnb + 4 * D, wkS, wvoS, Kall, Vall);

    // lnA == h16, xB == x4
    attn_g<<<1536, 256, 0, stream>>>(lnA, wqS, Kall, Vall, xpart);

    ffn_ln<<<ROWS / 64, 256, 0, stream>>>(xB, xpart, lng + 5 * D, lnb + 5 * D,
                                          w1S, b1, w2S, b2, out);
}

// Round 22
// 275.504 us; speedup vs baseline: 1.0338x; 1.0338x over previous
//
#include <hip/hip_runtime.h>
#include <math.h>

// EmbeddingEncoder: B=128, S=384, D=96, H=4, K=7, L=4.
// Round 22: attention with 48 q-rows/wave (3 m-tiles) on the r18 64-key LDS-staged
// base -> 3 MFMAs per ds_read_b128 (LDS port was co-throttling at 2:1), K/V fetch
// redundancy 3x->2x (grid 1024). conv3p V' store back to r18 64-key layout.

constexpr int B = 128;
constexpr int S = 384;
constexpr int D = 96;
constexpr int H = 4;
constexpr int KW = 7;
constexpr int L = 4;
constexpr int ROWS = B * S;                      // 49152
constexpr long long NTOT = (long long)ROWS * D;  // 4718592
constexpr float SQRTD = 9.797958971132712f;

typedef _Float16 f16x8 __attribute__((ext_vector_type(8)));
typedef float f32x4 __attribute__((ext_vector_type(4)));
typedef unsigned short us;
typedef unsigned short us8 __attribute__((ext_vector_type(8)));

__device__ __forceinline__ us f2h(float f) {
    _Float16 h = (_Float16)f;
    return __builtin_bit_cast(us, h);
}
__device__ __forceinline__ f16x8 ldh(const us* p) {
    return *reinterpret_cast<const f16x8*>(p);
}

// ---------------- positional encoding ----------------
__global__ void pe_kernel(float* __restrict__ pe) {
    int idx = blockIdx.x * 256 + threadIdx.x;
    if (idx >= S * D) return;
    int s = idx / D, c = idx - s * D;
    int j = c >> 1;
    float expo = (c & 1) ? (4.0f * j + 2.0f) / 96.0f : (4.0f * j) / 96.0f;
    float freq = expf(-expo * logf(10000.0f));
    float ang = (float)s * freq;
    pe[idx] = (c & 1) ? cosf(ang) : sinf(ang);
}

// ---------------- weight prep (ALL weights to fragment order) ----------------
__global__ void prep_w(const float* __restrict__ WQ, const float* __restrict__ WK,
                       const float* __restrict__ cpw, const float* __restrict__ w1,
                       const float* __restrict__ w2,
                       us* __restrict__ wqS, us* __restrict__ wkS, us* __restrict__ pwS,
                       us* __restrict__ w1S, us* __restrict__ w2S) {
    int idx = blockIdx.x * 256 + threadIdx.x;
    if (idx >= H * D * D) return;  // 36864
    int h = idx / (D * D), rem = idx - h * (D * D);
    int d = rem / D, e = rem - d * D;
    int n = e >> 4, lmod = e & 15, kk = d >> 5, ldiv = (d >> 3) & 3, j = d & 7;
    size_t fi = (size_t)(((n * 3 + kk) * 64 + ldiv * 16 + lmod) * 8 + j);
    wqS[(size_t)h * D * D + fi] = f2h(WQ[idx] * SQRTD);
    wkS[(size_t)h * D * D + fi] = f2h(WK[idx]);
    {
        int l = idx / (D * D);
        int o = rem / D, c = rem - o * D;
        int no = o >> 4, lo = o & 15, kc = c >> 5, lc = (c >> 3) & 3, jc = c & 7;
        pwS[(size_t)l * D * D + (size_t)(((no * 3 + kc) * 64 + lc * 16 + lo) * 8 + jc)] =
            f2h(cpw[idx]);
    }
    if (idx < 48 * 96) {
        int m = idx / 96, c = idx - m * 96;
        int nm = m >> 4, lm = m & 15, kc = c >> 5, lc = (c >> 3) & 3, jc = c & 7;
        w1S[((nm * 3 + kc) * 64 + lc * 16 + lm) * 8 + jc] = f2h(w1[c * 48 + m]);
    }
    if (idx < 96 * 64) {
        int o = idx / 64, mk = idx - o * 64;
        int no = o >> 4, lo = o & 15, km = mk >> 5, lm2 = (mk >> 3) & 3, jm = mk & 7;
        w2S[((no * 2 + km) * 64 + lm2 * 16 + lo) * 8 + jm] =
            (mk < 48) ? f2h(w2[mk * 96 + o]) : (us)0;
    }
}

// ---------------- WVO_h = WV_h @ WO_h -> fragment order ----------------
__global__ void prep_wvo(const float* __restrict__ WV, const float* __restrict__ WO,
                         us* __restrict__ wvoS) {
    int blk = blockIdx.x;  // 24 = H * 6
    int h = blk / 6, ot = blk - h * 6;
    int tid = threadIdx.x;
    const float* wv = WV + (size_t)h * D * D;
    const float* wo = WO + (size_t)h * D * D;
    for (int i = tid; i < 16 * 96; i += 256) {
        int lmod = i / 96, d = i - (i / 96) * 96;
        int o = ot * 16 + lmod;
        float acc = 0.f;
        for (int e = 0; e < 96; e++) acc += wv[d * 96 + e] * wo[e * 96 + o];
        int kk = d >> 5, ldiv = (d >> 3) & 3, j = d & 7;
        wvoS[(size_t)h * D * D + (size_t)(((ot * 3 + kk) * 64 + ldiv * 16 + lmod) * 8 + j)] =
            f2h(acc);
    }
}

// ---------------- conv0: embed + LN0 (halo inline) + dw + pw + residual + LN1 ----------------
__global__ void conv0f(const float* __restrict__ in, const float* __restrict__ pe,
                       const float* __restrict__ g0, const float* __restrict__ b0,
                       float* __restrict__ xout, us* __restrict__ lnout,
                       const float* __restrict__ dwW, const float* __restrict__ dwB,
                       const us* __restrict__ pwW, const float* __restrict__ pwb,
                       const float* __restrict__ gnext, const float* __restrict__ bnext) {
    __shared__ us lnb_s[70 * 104];
    __shared__ us dwb_s[64 * 104];
    __shared__ float lw[96 * 8];
    int tid = threadIdx.x;
    int wave = tid >> 6, lane = tid & 63;
    int r0 = blockIdx.x * 64;
    int b = r0 / S, s0 = r0 % S;

    for (int i = tid; i < 96 * KW; i += 256) lw[(i / KW) * 8 + (i % KW)] = dwW[i];

    for (int i = wave; i < 70; i += 4) {
        int s = s0 - 3 + i;
        bool valid = (unsigned)s < (unsigned)S;
        float v0 = 0.f, v1 = 0.f;
        if (valid) {
            size_t ro = ((size_t)b * S + s) * 96;
            v0 = in[ro + lane] * SQRTD + pe[s * 96 + lane];
            v1 = (lane < 32) ? in[ro + 64 + lane] * SQRTD + pe[s * 96 + 64 + lane] : 0.f;
        }
        float sm = v0 + v1, q = v0 * v0 + v1 * v1;
        for (int off = 32; off > 0; off >>= 1) {
            sm += __shfl_xor(sm, off);
            q += __shfl_xor(q, off);
        }
        float mean = sm * (1.0f / D);
        float var = q * (1.0f / D) - mean * mean;
        float rstd = rsqrtf(var + 1e-5f);
        lnb_s[i * 104 + lane] = f2h(valid ? (v0 - mean) * rstd * g0[lane] + b0[lane] : 0.f);
        if (lane < 32)
            lnb_s[i * 104 + 64 + lane] =
                f2h(valid ? (v1 - mean) * rstd * g0[lane + 64] + b0[lane + 64] : 0.f);
    }
    __syncthreads();

    for (int u = tid; u < 768; u += 256) {
        int j = u / 12, c0 = (u - (u / 12) * 12) * 8;
        float acc[8];
        #pragma unroll
        for (int j2 = 0; j2 < 8; j2++) acc[j2] = dwB[c0 + j2];
        #pragma unroll
        for (int k = 0; k < KW; k++) {
            f16x8 v = ldh(&lnb_s[(j + k) * 104 + c0]);
            #pragma unroll
            for (int j2 = 0; j2 < 8; j2++) acc[j2] += (float)v[j2] * lw[(c0 + j2) * 8 + k];
        }
        us8 o;
        #pragma unroll
        for (int j2 = 0; j2 < 8; j2++) o[j2] = f2h(acc[j2]);
        *reinterpret_cast<us8*>(&dwb_s[j * 104 + c0]) = o;
    }
    __syncthreads();

    int lmod = lane & 15, ldiv = lane >> 4, m0 = wave * 16;
    f32x4 acc[6] = {};
    #pragma unroll
    for (int kk = 0; kk < 3; kk++) {
        f16x8 af = ldh(&dwb_s[(m0 + lmod) * 104 + kk * 32 + ldiv * 8]);
        #pragma unroll
        for (int n = 0; n < 6; n++) {
            f16x8 bf = ldh(pwW + (size_t)((n * 3 + kk) * 64) * 8 + lane * 8);
            acc[n] = __builtin_amdgcn_mfma_f32_16x16x32_f16(af, bf, acc[n], 0, 0, 0);
        }
    }

    float gv[6], bv2[6], pb[6];
    #pragma unroll
    for (int n = 0; n < 6; n++) {
        int o = n * 16 + lmod;
        gv[n] = gnext[o];
        bv2[n] = bnext[o];
        pb[n] = pwb[o];
    }
    #pragma unroll
    for (int n = 0; n < 6; n++) {
        int o = n * 16 + lmod;
        #pragma unroll
        for (int r = 0; r < 4; r++) {
            int sr = m0 + ldiv * 4 + r;
            size_t row = (size_t)r0 + sr;
            float base = in[row * 96 + o] * SQRTD + pe[(s0 + sr) * 96 + o];
            acc[n][r] = base + fmaxf(acc[n][r] + pb[n], 0.f);
        }
    }
    #pragma unroll
    for (int r = 0; r < 4; r++) {
        float sm = 0.f, qq = 0.f;
        #pragma unroll
        for (int n = 0; n < 6; n++) {
            sm += acc[n][r];
            qq += acc[n][r] * acc[n][r];
        }
        #pragma unroll
        for (int st = 1; st <= 8; st <<= 1) {
            sm += __shfl_xor(sm, st);
            qq += __shfl_xor(qq, st);
        }
        float mean = sm * (1.0f / D);
        float var = qq * (1.0f / D) - mean * mean;
        float rstd = rsqrtf(var + 1e-5f);
        size_t row = (size_t)r0 + m0 + ldiv * 4 + r;
        #pragma unroll
        for (int n = 0; n < 6; n++) {
            int o = n * 16 + lmod;
            xout[row * 96 + o] = acc[n][r];
            lnout[row * 96 + o] = f2h((acc[n][r] - mean) * rstd * gv[n] + bv2[n]);
        }
    }
}

// ---------------- mid conv layer ----------------
__global__ void conv2(const float* __restrict__ xin, const us* __restrict__ lnin,
                      float* __restrict__ xout, us* __restrict__ lnout,
                      const float* __restrict__ dwW, const float* __restrict__ dwB,
                      const us* __restrict__ pwW, const float* __restrict__ pwb,
                      const float* __restrict__ gnext, const float* __restrict__ bnext) {
    __shared__ us dwb_s[64 * 104];
    __shared__ float lw[96 * 8];
    int tid = threadIdx.x;
    int wave = tid >> 6, lane = tid & 63;
    int r0 = blockIdx.x * 64;
    int b = r0 / S, s0 = r0 % S;

    for (int i = tid; i < 96 * KW; i += 256) lw[(i / KW) * 8 + (i % KW)] = dwW[i];
    __syncthreads();

    for (int u = tid; u < 768; u += 256) {
        int j = u / 12, c0 = (u - (u / 12) * 12) * 8;
        float acc[8];
        #pragma unroll
        for (int j2 = 0; j2 < 8; j2++) acc[j2] = dwB[c0 + j2];
        #pragma unroll
        for (int k = 0; k < KW; k++) {
            int ss = s0 + j + k - 3;
            if ((unsigned)ss < (unsigned)S) {
                f16x8 v = ldh(lnin + ((size_t)b * S + ss) * 96 + c0);
                #pragma unroll
                for (int j2 = 0; j2 < 8; j2++) acc[j2] += (float)v[j2] * lw[(c0 + j2) * 8 + k];
            }
        }
        us8 o;
        #pragma unroll
        for (int j2 = 0; j2 < 8; j2++) o[j2] = f2h(acc[j2]);
        *reinterpret_cast<us8*>(&dwb_s[j * 104 + c0]) = o;
    }
    __syncthreads();

    int lmod = lane & 15, ldiv = lane >> 4, m0 = wave * 16;
    f32x4 acc[6] = {};
    #pragma unroll
    for (int kk = 0; kk < 3; kk++) {
        f16x8 af = ldh(&dwb_s[(m0 + lmod) * 104 + kk * 32 + ldiv * 8]);
        #pragma unroll
        for (int n = 0; n < 6; n++) {
            f16x8 bf = ldh(pwW + (size_t)((n * 3 + kk) * 64) * 8 + lane * 8);
            acc[n] = __builtin_amdgcn_mfma_f32_16x16x32_f16(af, bf, acc[n], 0, 0, 0);
        }
    }

    float gv[6], bv2[6], pb[6];
    #pragma unroll
    for (int n = 0; n < 6; n++) {
        int o = n * 16 + lmod;
        gv[n] = gnext[o];
        bv2[n] = bnext[o];
        pb[n] = pwb[o];
    }
    #pragma unroll
    for (int n = 0; n < 6; n++) {
        #pragma unroll
        for (int r = 0; r < 4; r++) {
            size_t row = (size_t)r0 + m0 + ldiv * 4 + r;
            acc[n][r] = xin[row * 96 + n * 16 + lmod] + fmaxf(acc[n][r] + pb[n], 0.f);
        }
    }
    #pragma unroll
    for (int r = 0; r < 4; r++) {
        float sm = 0.f, qq = 0.f;
        #pragma unroll
        for (int n = 0; n < 6; n++) {
            sm += acc[n][r];
            qq += acc[n][r] * acc[n][r];
        }
        #pragma unroll
        for (int st = 1; st <= 8; st <<= 1) {
            sm += __shfl_xor(sm, st);
            qq += __shfl_xor(qq, st);
        }
        float mean = sm * (1.0f / D);
        float var = qq * (1.0f / D) - mean * mean;
        float rstd = rsqrtf(var + 1e-5f);
        size_t row = (size_t)r0 + m0 + ldiv * 4 + r;
        #pragma unroll
        for (int n = 0; n < 6; n++) {
            int o = n * 16 + lmod;
            xout[row * 96 + o] = acc[n][r];
            lnout[row * 96 + o] = f2h((acc[n][r] - mean) * rstd * gv[n] + bv2[n]);
        }
    }
}

// ---------------- conv3 + K/V' projection fused (V 64-key-chunk layout, r18) ----------------
__global__ void conv3p(const float* __restrict__ xin, const us* __restrict__ lnin,
                       float* __restrict__ xout, us* __restrict__ lnout,
                       const float* __restrict__ dwW, const float* __restrict__ dwB,
                       const us* __restrict__ pwW, const float* __restrict__ pwb,
                       const float* __restrict__ gnext, const float* __restrict__ bnext,
                       const us* __restrict__ wkS, const us* __restrict__ wvoS,
                       us* __restrict__ Kall, us* __restrict__ Vall) {
    __shared__ float lw[96 * 8];
    __shared__ us stg[96 * 72];
    __shared__ us lnstg[64 * 104];
    int tid = threadIdx.x;
    int wave = tid >> 6, lane = tid & 63;
    int lmod = lane & 15, ldiv = lane >> 4, m0 = wave * 16;
    int r0 = blockIdx.x * 64;
    int b = r0 / S, s0 = r0 % S;

    for (int i = tid; i < 96 * KW; i += 256) lw[(i / KW) * 8 + (i % KW)] = dwW[i];
    __syncthreads();

    for (int u = tid; u < 768; u += 256) {
        int j = u / 12, c0 = (u - (u / 12) * 12) * 8;
        float acc[8];
        #pragma unroll
        for (int j2 = 0; j2 < 8; j2++) acc[j2] = dwB[c0 + j2];
        #pragma unroll
        for (int k = 0; k < KW; k++) {
            int ss = s0 + j + k - 3;
            if ((unsigned)ss < (unsigned)S) {
                f16x8 v = ldh(lnin + ((size_t)b * S + ss) * 96 + c0);
                #pragma unroll
                for (int j2 = 0; j2 < 8; j2++) acc[j2] += (float)v[j2] * lw[(c0 + j2) * 8 + k];
            }
        }
        us8 o;
        #pragma unroll
        for (int j2 = 0; j2 < 8; j2++) o[j2] = f2h(acc[j2]);
        *reinterpret_cast<us8*>(&stg[j * 104 + c0]) = o;
    }
    __syncthreads();

    f32x4 acc[6] = {};
    #pragma unroll
    for (int kk = 0; kk < 3; kk++) {
        f16x8 af = ldh(&stg[(m0 + lmod) * 104 + kk * 32 + ldiv * 8]);
        #pragma unroll
        for (int n = 0; n < 6; n++) {
            f16x8 bf = ldh(pwW + (size_t)((n * 3 + kk) * 64) * 8 + lane * 8);
            acc[n] = __builtin_amdgcn_mfma_f32_16x16x32_f16(af, bf, acc[n], 0, 0, 0);
        }
    }

    float gv[6], bv2[6], pb[6];
    #pragma unroll
    for (int n = 0; n < 6; n++) {
        int o = n * 16 + lmod;
        gv[n] = gnext[o];
        bv2[n] = bnext[o];
        pb[n] = pwb[o];
    }
    #pragma unroll
    for (int n = 0; n < 6; n++) {
        #pragma unroll
        for (int r = 0; r < 4; r++) {
            size_t row = (size_t)r0 + m0 + ldiv * 4 + r;
            acc[n][r] = xin[row * 96 + n * 16 + lmod] + fmaxf(acc[n][r] + pb[n], 0.f);
        }
    }
    #pragma unroll
    for (int r = 0; r < 4; r++) {
        float sm = 0.f, qq = 0.f;
        #pragma unroll
        for (int n = 0; n < 6; n++) {
            sm += acc[n][r];
            qq += acc[n][r] * acc[n][r];
        }
        #pragma unroll
        for (int st = 1; st <= 8; st <<= 1) {
            sm += __shfl_xor(sm, st);
            qq += __shfl_xor(qq, st);
        }
        float mean = sm * (1.0f / D);
        float var = qq * (1.0f / D) - mean * mean;
        float rstd = rsqrtf(var + 1e-5f);
        size_t row = (size_t)r0 + m0 + ldiv * 4 + r;
        #pragma unroll
        for (int n = 0; n < 6; n++) {
            int o = n * 16 + lmod;
            xout[row * 96 + o] = acc[n][r];
            us hv = f2h((acc[n][r] - mean) * rstd * gv[n] + bv2[n]);
            lnout[row * 96 + o] = hv;
            lnstg[(m0 + ldiv * 4 + r) * 104 + o] = hv;
        }
    }
    __syncthreads();

    f16x8 af[3];
    #pragma unroll
    for (int kk = 0; kk < 3; kk++)
        af[kk] = ldh(&lnstg[(m0 + lmod) * 104 + kk * 32 + ldiv * 8]);

    for (int hd = 0; hd < H; hd++) {
        // ---- K ----
        f32x4 ka[6] = {};
        #pragma unroll
        for (int kk = 0; kk < 3; kk++)
            #pragma unroll
            for (int n = 0; n < 6; n++) {
                f16x8 bf = ldh(wkS + (size_t)hd * D * D + (size_t)((n * 3 + kk) * 64) * 8 + lane * 8);
                ka[n] = __builtin_amdgcn_mfma_f32_16x16x32_f16(af[kk], bf, ka[n], 0, 0, 0);
            }
        __syncthreads();
        us* kT = stg + wave * 1664;
        #pragma unroll
        for (int n = 0; n < 6; n++)
            #pragma unroll
            for (int r = 0; r < 4; r++)
                kT[(ldiv * 4 + r) * 104 + n * 16 + lmod] = f2h(ka[n][r]);
        int t0 = (r0 % S) / 16 + wave;
        us* dst = Kall + (size_t)hd * NTOT + ((size_t)(b * 24 + t0) * 3) * 512;
        #pragma unroll
        for (int kk = 0; kk < 3; kk++) {
            us8 v = *reinterpret_cast<const us8*>(&kT[lmod * 104 + kk * 32 + ldiv * 8]);
            *reinterpret_cast<us8*>(dst + kk * 512 + lane * 8) = v;
        }
        // ---- V' ---- 64-key-chunk layout: [b][cblk(6)][n(6)][kk(2)][512]
        f32x4 va[6] = {};
        #pragma unroll
        for (int kk = 0; kk < 3; kk++)
            #pragma unroll
            for (int n = 0; n < 6; n++) {
                f16x8 bf =
                    ldh(wvoS + (size_t)hd * D * D + (size_t)((n * 3 + kk) * 64) * 8 + lane * 8);
                va[n] = __builtin_amdgcn_mfma_f32_16x16x32_f16(af[kk], bf, va[n], 0, 0, 0);
            }
        __syncthreads();
        #pragma unroll
        for (int n = 0; n < 6; n++)
            #pragma unroll
            for (int r = 0; r < 4; r++)
                stg[(n * 16 + lmod) * 72 + m0 + ldiv * 4 + r] = f2h(va[n][r]);
        __syncthreads();
        int cblk = (r0 % S) / 64;
        us* dsth = Vall + (size_t)hd * NTOT;
        #pragma unroll
        for (int n = 0; n < 6; n++)
            #pragma unroll
            for (int kk = 0; kk < 2; kk++) {
                us8 v =
                    *reinterpret_cast<const us8*>(&stg[(n * 16 + lmod) * 72 + kk * 32 + ldiv * 8]);
                *reinterpret_cast<us8*>(
                    dsth + ((size_t)((b * 6 + cblk) * 6 + n) * 2 + kk) * 512 + lane * 8) = v;
            }
    }
}

// ---------------- block-cooperative LDS-staged attention, 3 m-tiles/wave ----------------
// grid 1024 = 128 b x 4 hd x 2 qhalf; 4 waves x 48 q-rows; 64-key chunks, K/V dbuf.
__global__ __launch_bounds__(256, 2) void attn_g(const us* __restrict__ h16,
                                                 const us* __restrict__ wqS,
                                                 const us* __restrict__ Kall,
                                                 const us* __restrict__ Vall,
                                                 us* __restrict__ xpart) {
    __shared__ us pool[38400];  // Kb:0/6144 | Vb:12288/18432 | P:24576+wave*3456 ; prologue Qstage: wave*4992
    int tid = threadIdx.x, wave = tid >> 6, lane = tid & 63;
    int lmod = lane & 15, ldiv = lane >> 4;
    int p = blockIdx.x;
    int gl = (p & 7) * 128 + (p >> 3);  // XCD swizzle, 1024 = 8*128
    int qt = gl & 1;
    int bh = gl >> 1;
    int b = bh >> 2, hd = bh & 3;
    size_t rowbase = (size_t)b * S + qt * 192 + wave * 48;

    const us* Kh = Kall + (size_t)hd * NTOT + (size_t)b * 24 * 1536;
    const us* Vh = Vall + (size_t)hd * NTOT + (size_t)b * 36 * 1024;
    us* P = pool + 24576 + wave * 3456;  // [48][72]

    // prologue: issue K0 staging loads; Q-proj under their latency
    us8 k0s[3];
    #pragma unroll
    for (int j = 0; j < 3; j++)
        k0s[j] = *reinterpret_cast<const us8*>(Kh + (size_t)(j * 256 + tid) * 8);

    f32x4 qa0[6] = {}, qa1[6] = {}, qa2[6] = {};
    #pragma unroll
    for (int kk = 0; kk < 3; kk++) {
        f16x8 a0 = ldh(h16 + (rowbase + lmod) * 96 + kk * 32 + ldiv * 8);
        f16x8 a1 = ldh(h16 + (rowbase + 16 + lmod) * 96 + kk * 32 + ldiv * 8);
        f16x8 a2 = ldh(h16 + (rowbase + 32 + lmod) * 96 + kk * 32 + ldiv * 8);
        #pragma unroll
        for (int n = 0; n < 6; n++) {
            f16x8 bf = ldh(wqS + (size_t)hd * D * D + (size_t)((n * 3 + kk) * 64) * 8 + lane * 8);
            qa0[n] = __builtin_amdgcn_mfma_f32_16x16x32_f16(a0, bf, qa0[n], 0, 0, 0);
            qa1[n] = __builtin_amdgcn_mfma_f32_16x16x32_f16(a1, bf, qa1[n], 0, 0, 0);
            qa2[n] = __builtin_amdgcn_mfma_f32_16x16x32_f16(a2, bf, qa2[n], 0, 0, 0);
        }
    }
    us* qst = pool + wave * 4992;  // [48][104], wave-private (overlaps Kb/Vb; barrier below)
    #pragma unroll
    for (int n = 0; n < 6; n++)
        #pragma unroll
        for (int r = 0; r < 4; r++) {
            qst[(ldiv * 4 + r) * 104 + n * 16 + lmod] = f2h(qa0[n][r]);
            qst[(16 + ldiv * 4 + r) * 104 + n * 16 + lmod] = f2h(qa1[n][r]);
            qst[(32 + ldiv * 4 + r) * 104 + n * 16 + lmod] = f2h(qa2[n][r]);
        }
    f16x8 aq0[3], aq1[3], aq2[3];
    #pragma unroll
    for (int kk = 0; kk < 3; kk++) {
        aq0[kk] = ldh(&qst[lmod * 104 + kk * 32 + ldiv * 8]);
        aq1[kk] = ldh(&qst[(16 + lmod) * 104 + kk * 32 + ldiv * 8]);
        aq2[kk] = ldh(&qst[(32 + lmod) * 104 + kk * 32 + ldiv * 8]);
    }
    __syncthreads();  // all waves done with Q staging in pool
    #pragma unroll
    for (int j = 0; j < 3; j++)
        *reinterpret_cast<us8*>(&pool[(j * 256 + tid) * 8]) = k0s[j];
    __syncthreads();

    // ---- pass 1: row max (6 chunks of 64 keys) ----
    f32x4 mx0 = {-1e30f, -1e30f, -1e30f, -1e30f}, mx1 = mx0, mx2 = mx0;
    for (int c = 0; c < 6; c++) {
        us* kbc = pool + (c & 1) * 6144;
        us8 kn[3], vn[3];
        bool last = (c == 5);
        if (!last) {
            const us* src = Kh + (size_t)(c + 1) * 6144;
            #pragma unroll
            for (int j = 0; j < 3; j++)
                kn[j] = *reinterpret_cast<const us8*>(src + (size_t)(j * 256 + tid) * 8);
        } else {
            #pragma unroll
            for (int j = 0; j < 3; j++) {
                kn[j] = *reinterpret_cast<const us8*>(Kh + (size_t)(j * 256 + tid) * 8);
                vn[j] = *reinterpret_cast<const us8*>(Vh + (size_t)(j * 256 + tid) * 8);
            }
        }
        __builtin_amdgcn_s_setprio(1);
        f32x4 s0[4] = {}, s1[4] = {}, s2[4] = {};
        #pragma unroll
        for (int nt = 0; nt < 4; nt++)
            #pragma unroll
            for (int kk = 0; kk < 3; kk++) {
                f16x8 bf = ldh(&kbc[(nt * 3 + kk) * 512 + lane * 8]);
                s0[nt] = __builtin_amdgcn_mfma_f32_16x16x32_f16(aq0[kk], bf, s0[nt], 0, 0, 0);
                s1[nt] = __builtin_amdgcn_mfma_f32_16x16x32_f16(aq1[kk], bf, s1[nt], 0, 0, 0);
                s2[nt] = __builtin_amdgcn_mfma_f32_16x16x32_f16(aq2[kk], bf, s2[nt], 0, 0, 0);
            }
        __builtin_amdgcn_s_setprio(0);
        #pragma unroll
        for (int nt = 0; nt < 4; nt++)
            #pragma unroll
            for (int r = 0; r < 4; r++) {
                mx0[r] = fmaxf(mx0[r], s0[nt][r]);
                mx1[r] = fmaxf(mx1[r], s1[nt][r]);
                mx2[r] = fmaxf(mx2[r], s2[nt][r]);
            }
        us* kbw = pool + (last ? 0 : ((c & 1) ^ 1)) * 6144;
        #pragma unroll
        for (int j = 0; j < 3; j++)
            *reinterpret_cast<us8*>(&kbw[(j * 256 + tid) * 8]) = kn[j];
        if (last) {
            #pragma unroll
            for (int j = 0; j < 3; j++)
                *reinterpret_cast<us8*>(&pool[12288 + (j * 256 + tid) * 8]) = vn[j];
        }
        __syncthreads();
    }
    #pragma unroll
    for (int st = 1; st <= 8; st <<= 1)
        #pragma unroll
        for (int r = 0; r < 4; r++) {
            mx0[r] = fmaxf(mx0[r], __shfl_xor(mx0[r], st));
            mx1[r] = fmaxf(mx1[r], __shfl_xor(mx1[r], st));
            mx2[r] = fmaxf(mx2[r], __shfl_xor(mx2[r], st));
        }

    // ---- pass 2: scores -> exp -> PV ----
    f32x4 oacc0[6] = {}, oacc1[6] = {}, oacc2[6] = {};
    f32x4 l0v = {}, l1v = {}, l2v = {};
    for (int c = 0; c < 6; c++) {
        us* kbc = pool + (c & 1) * 6144;
        us* vbc = pool + 12288 + (c & 1) * 6144;
        us8 kn[3], vn[3];
        if (c < 5) {
            const us* ksrc = Kh + (size_t)(c + 1) * 6144;
            const us* vsrc = Vh + (size_t)(c + 1) * 6144;
            #pragma unroll
            for (int j = 0; j < 3; j++) {
                kn[j] = *reinterpret_cast<const us8*>(ksrc + (size_t)(j * 256 + tid) * 8);
                vn[j] = *reinterpret_cast<const us8*>(vsrc + (size_t)(j * 256 + tid) * 8);
            }
        }
        __builtin_amdgcn_s_setprio(1);
        f32x4 s0[4] = {}, s1[4] = {}, s2[4] = {};
        #pragma unroll
        for (int nt = 0; nt < 4; nt++)
            #pragma unroll
            for (int kk = 0; kk < 3; kk++) {
                f16x8 bf = ldh(&kbc[(nt * 3 + kk) * 512 + lane * 8]);
                s0[nt] = __builtin_amdgcn_mfma_f32_16x16x32_f16(aq0[kk], bf, s0[nt], 0, 0, 0);
                s1[nt] = __builtin_amdgcn_mfma_f32_16x16x32_f16(aq1[kk], bf, s1[nt], 0, 0, 0);
                s2[nt] = __builtin_amdgcn_mfma_f32_16x16x32_f16(aq2[kk], bf, s2[nt], 0, 0, 0);
            }
        __builtin_amdgcn_s_setprio(0);
        #pragma unroll
        for (int nt = 0; nt < 4; nt++)
            #pragma unroll
            for (int r = 0; r < 4; r++) {
                float p0 = __expf(s0[nt][r] - mx0[r]);
                float p1 = __expf(s1[nt][r] - mx1[r]);
                float p2 = __expf(s2[nt][r] - mx2[r]);
                l0v[r] += p0;
                l1v[r] += p1;
                l2v[r] += p2;
                P[(ldiv * 4 + r) * 72 + nt * 16 + lmod] = f2h(p0);
                P[(16 + ldiv * 4 + r) * 72 + nt * 16 + lmod] = f2h(p1);
                P[(32 + ldiv * 4 + r) * 72 + nt * 16 + lmod] = f2h(p2);
            }
        __builtin_amdgcn_s_setprio(1);
        #pragma unroll
        for (int kk = 0; kk < 2; kk++) {
            f16x8 pf0 = ldh(&P[lmod * 72 + kk * 32 + ldiv * 8]);
            f16x8 pf1 = ldh(&P[(16 + lmod) * 72 + kk * 32 + ldiv * 8]);
            f16x8 pf2 = ldh(&P[(32 + lmod) * 72 + kk * 32 + ldiv * 8]);
            #pragma unroll
            for (int n = 0; n < 6; n++) {
                f16x8 bf = ldh(&vbc[(n * 2 + kk) * 512 + lane * 8]);
                oacc0[n] = __builtin_amdgcn_mfma_f32_16x16x32_f16(pf0, bf, oacc0[n], 0, 0, 0);
                oacc1[n] = __builtin_amdgcn_mfma_f32_16x16x32_f16(pf1, bf, oacc1[n], 0, 0, 0);
                oacc2[n] = __builtin_amdgcn_mfma_f32_16x16x32_f16(pf2, bf, oacc2[n], 0, 0, 0);
            }
        }
        __builtin_amdgcn_s_setprio(0);
        if (c < 5) {
            us* kbn = pool + ((c & 1) ^ 1) * 6144;
            us* vbn = pool + 12288 + ((c & 1) ^ 1) * 6144;
            #pragma unroll
            for (int j = 0; j < 3; j++) {
                *reinterpret_cast<us8*>(&kbn[(j * 256 + tid) * 8]) = kn[j];
                *reinterpret_cast<us8*>(&vbn[(j * 256 + tid) * 8]) = vn[j];
            }
            __syncthreads();
        }
    }
    #pragma unroll
    for (int st = 1; st <= 8; st <<= 1)
        #pragma unroll
        for (int r = 0; r < 4; r++) {
            l0v[r] += __shfl_xor(l0v[r], st);
            l1v[r] += __shfl_xor(l1v[r], st);
            l2v[r] += __shfl_xor(l2v[r], st);
        }

    us* xp = xpart + (size_t)hd * NTOT;
    #pragma unroll
    for (int r = 0; r < 4; r++) {
        float inv0 = 1.f / l0v[r];
        float inv1 = 1.f / l1v[r];
        float inv2 = 1.f / l2v[r];
        #pragma unroll
        for (int n = 0; n < 6; n++) {
            xp[(rowbase + ldiv * 4 + r) * 96 + n * 16 + lmod] = f2h(oacc0[n][r] * inv0);
            xp[(rowbase + 16 + ldiv * 4 + r) * 96 + n * 16 + lmod] = f2h(oacc1[n][r] * inv1);
            xp[(rowbase + 32 + ldiv * 4 + r) * 96 + n * 16 + lmod] = f2h(oacc2[n][r] * inv2);
        }
    }
}

// ---------------- fused head-reduce + LN + FFN ----------------
__global__ void ffn_ln(const float* __restrict__ x, const us* __restrict__ xpart,
                       const float* __restrict__ gln, const float* __restrict__ bln,
                       const us* __restrict__ w1S, const float* __restrict__ b1,
                       const us* __restrict__ w2S, const float* __restrict__ b2,
                       float* __restrict__ out) {
    __shared__ float xf[64 * 96];
    __shared__ us lnb[64 * 104];
    __shared__ us mid[64 * 72];
    int tid = threadIdx.x, wave = tid >> 6, lane = tid & 63;
    int lmod = lane & 15, ldiv = lane >> 4, m0 = wave * 16;
    int row0 = blockIdx.x * 64;

    for (int i = wave; i < 64; i += 4) {
        size_t ro = (size_t)(row0 + i) * 96;
        float v0 = x[ro + lane];
        float v1 = (lane < 32) ? x[ro + 64 + lane] : 0.f;
        #pragma unroll
        for (int h = 0; h < H; h++) {
            const us* xp = xpart + (size_t)h * NTOT + ro;
            v0 += (float)__builtin_bit_cast(_Float16, xp[lane]);
            if (lane < 32) v1 += (float)__builtin_bit_cast(_Float16, xp[64 + lane]);
        }
        xf[i * 96 + lane] = v0;
        if (lane < 32) xf[i * 96 + 64 + lane] = v1;
        float sm = v0 + v1, q = v0 * v0 + v1 * v1;
        for (int off = 32; off > 0; off >>= 1) {
            sm += __shfl_xor(sm, off);
            q += __shfl_xor(q, off);
        }
        float mean = sm * (1.0f / D);
        float var = q * (1.0f / D) - mean * mean;
        float rstd = rsqrtf(var + 1e-5f);
        lnb[i * 104 + lane] = f2h((v0 - mean) * rstd * gln[lane] + bln[lane]);
        if (lane < 32)
            lnb[i * 104 + 64 + lane] = f2h((v1 - mean) * rstd * gln[lane + 64] + bln[lane + 64]);
    }
    __syncthreads();

    f32x4 a3[3] = {};
    #pragma unroll
    for (int kk = 0; kk < 3; kk++) {
        f16x8 af = ldh(&lnb[(m0 + lmod) * 104 + kk * 32 + ldiv * 8]);
        #pragma unroll
        for (int n = 0; n < 3; n++) {
            f16x8 bf = ldh(w1S + (size_t)((n * 3 + kk) * 64) * 8 + lane * 8);
            a3[n] = __builtin_amdgcn_mfma_f32_16x16x32_f16(af, bf, a3[n], 0, 0, 0);
        }
    }
    #pragma unroll
    for (int n = 0; n < 3; n++) {
        float bv = b1[n * 16 + lmod];
        #pragma unroll
        for (int r = 0; r < 4; r++) {
            float v = a3[n][r] + bv;
            mid[(m0 + ldiv * 4 + r) * 72 + n * 16 + lmod] = f2h(1.f / (1.f + __expf(-v)));
        }
    }
    #pragma unroll
    for (int r = 0; r < 4; r++) mid[(m0 + ldiv * 4 + r) * 72 + 48 + lmod] = 0;
    __syncthreads();

    f32x4 a6[6] = {};
    #pragma unroll
    for (int kk = 0; kk < 2; kk++) {
        f16x8 af = ldh(&mid[(m0 + lmod) * 72 + kk * 32 + ldiv * 8]);
        #pragma unroll
        for (int n = 0; n < 6; n++) {
            f16x8 bf = ldh(w2S + (size_t)((n * 2 + kk) * 64) * 8 + lane * 8);
            a6[n] = __builtin_amdgcn_mfma_f32_16x16x32_f16(af, bf, a6[n], 0, 0, 0);
        }
    }
    #pragma unroll
    for (int n = 0; n < 6; n++) {
        int o = n * 16 + lmod;
        float bv = b2[o];
        #pragma unroll
        for (int r = 0; r < 4; r++) {
            int sr = m0 + ldiv * 4 + r;
            out[(size_t)(row0 + sr) * 96 + o] = xf[sr * 96 + o] + a6[n][r] + bv;
        }
    }
}

extern "C" void kernel_launch(void* const* d_in, const int* in_sizes, int n_in,
                              void* d_out, int out_size, void* d_ws, size_t ws_size,
                              hipStream_t stream) {
    const float* in   = (const float*)d_in[0];
    const float* cdw  = (const float*)d_in[2];
    const float* cdwb = (const float*)d_in[3];
    const float* cpw  = (const float*)d_in[4];
    const float* cpwb = (const float*)d_in[5];
    const float* WQ   = (const float*)d_in[6];
    const float* WK   = (const float*)d_in[7];
    const float* WV   = (const float*)d_in[8];
    const float* WO   = (const float*)d_in[9];
    const float* w1   = (const float*)d_in[10];
    const float* b1   = (const float*)d_in[11];
    const float* w2   = (const float*)d_in[12];
    const float* b2   = (const float*)d_in[13];
    const float* lng  = (const float*)d_in[14];
    const float* lnb  = (const float*)d_in[15];
    float* out = (float*)d_out;
    float* ws = (float*)d_ws;

    float* xA  = ws;
    float* xB  = xA + NTOT;
    float* pe  = xB + NTOT;
    us* lnA    = (us*)(pe + S * D);
    us* lnB    = lnA + NTOT;
    us* Kall   = lnB + NTOT;               // [H][B][24][3][64][8]
    us* Vall   = Kall + (size_t)H * NTOT;  // [H][B][6 cblk][6 n][2 kk][512]
    us* xpart  = Vall + (size_t)H * NTOT;  // [H][ROWS][96]
    us* wqS    = xpart + (size_t)H * NTOT;
    us* wkS    = wqS + H * D * D;
    us* wvoS   = wkS + H * D * D;
    us* pwS    = wvoS + H * D * D;
    us* w1S    = pwS + L * D * D;
    us* w2S    = w1S + 48 * 96;
    // total ~= 170 MB (< 256 MB ws)

    pe_kernel<<<(S * D + 255) / 256, 256, 0, stream>>>(pe);
    prep_w<<<(H * D * D + 255) / 256, 256, 0, stream>>>(WQ, WK, cpw, w1, w2,
                                                        wqS, wkS, pwS, w1S, w2S);
    prep_wvo<<<H * 6, 256, 0, stream>>>(WV, WO, wvoS);

    conv0f<<<ROWS / 64, 256, 0, stream>>>(in, pe, lng, lnb, xA, lnB,
                                          cdw, cdwb, pwS, cpwb, lng + D, lnb + D);
    conv2<<<ROWS / 64, 256, 0, stream>>>(xA, lnB, xB, lnA, cdw + D * KW, cdwb + D,
                                         pwS + D * D, cpwb + D, lng + 2 * D, lnb + 2 * D);
    conv2<<<ROWS / 64, 256, 0, stream>>>(xB, lnA, xA, lnB, cdw + 2 * D * KW, cdwb + 2 * D,
                                         pwS + 2 * D * D, cpwb + 2 * D, lng + 3 * D,
                                         lnb + 3 * D);
    conv3p<<<ROWS / 64, 256, 0, stream>>>(xA, lnB, xB, lnA, cdw + 3 * D * KW, cdwb + 3 * D,
                                          pwS + 3 * D * D, cpwb + 3 * D, lng + 4 * D,
                                          lnb + 4 * D, wkS, wvoS, Kall, Vall);

    // lnA == h16, xB == x4
    attn_g<<<1024, 256, 0, stream>>>(lnA, wqS, Kall, Vall, xpart);

    ffn_ln<<<ROWS / 64, 256, 0, stream>>>(xB, xpart, lng + 5 * D, lnb + 5 * D,
                                          w1S, b1, w2S, b2, out);
}

// Round 23
// 274.640 us; speedup vs baseline: 1.0370x; 1.0031x over previous
//
#include <hip/hip_runtime.h>
#include <math.h>

// EmbeddingEncoder: B=128, S=384, D=96, H=4, K=7, L=4.
// Round 23: swapped-operand QK^T in attention (mfma(K,Q)) -> lane holds contiguous
// k for its q-row: P written as packed b64 (12/chunk vs 48 scalar b16), max/sum as
// scalar in-reg trees + 2 shuffles, exp2 with log2e prefolded into wqS.

constexpr int B = 128;
constexpr int S = 384;
constexpr int D = 96;
constexpr int H = 4;
constexpr int KW = 7;
constexpr int L = 4;
constexpr int ROWS = B * S;                      // 49152
constexpr long long NTOT = (long long)ROWS * D;  // 4718592
constexpr float SQRTD = 9.797958971132712f;
constexpr float LOG2E = 1.4426950408889634f;

typedef _Float16 f16x8 __attribute__((ext_vector_type(8)));
typedef float f32x4 __attribute__((ext_vector_type(4)));
typedef unsigned short us;
typedef unsigned short us4 __attribute__((ext_vector_type(4)));
typedef unsigned short us8 __attribute__((ext_vector_type(8)));

__device__ __forceinline__ us f2h(float f) {
    _Float16 h = (_Float16)f;
    return __builtin_bit_cast(us, h);
}
__device__ __forceinline__ f16x8 ldh(const us* p) {
    return *reinterpret_cast<const f16x8*>(p);
}

// ---------------- positional encoding ----------------
__global__ void pe_kernel(float* __restrict__ pe) {
    int idx = blockIdx.x * 256 + threadIdx.x;
    if (idx >= S * D) return;
    int s = idx / D, c = idx - s * D;
    int j = c >> 1;
    float expo = (c & 1) ? (4.0f * j + 2.0f) / 96.0f : (4.0f * j) / 96.0f;
    float freq = expf(-expo * logf(10000.0f));
    float ang = (float)s * freq;
    pe[idx] = (c & 1) ? cosf(ang) : sinf(ang);
}

// ---------------- weight prep (ALL weights to fragment order) ----------------
__global__ void prep_w(const float* __restrict__ WQ, const float* __restrict__ WK,
                       const float* __restrict__ cpw, const float* __restrict__ w1,
                       const float* __restrict__ w2,
                       us* __restrict__ wqS, us* __restrict__ wkS, us* __restrict__ pwS,
                       us* __restrict__ w1S, us* __restrict__ w2S) {
    int idx = blockIdx.x * 256 + threadIdx.x;
    if (idx >= H * D * D) return;  // 36864
    int h = idx / (D * D), rem = idx - h * (D * D);
    int d = rem / D, e = rem - d * D;
    int n = e >> 4, lmod = e & 15, kk = d >> 5, ldiv = (d >> 3) & 3, j = d & 7;
    size_t fi = (size_t)(((n * 3 + kk) * 64 + ldiv * 16 + lmod) * 8 + j);
    wqS[(size_t)h * D * D + fi] = f2h(WQ[idx] * SQRTD * LOG2E);
    wkS[(size_t)h * D * D + fi] = f2h(WK[idx]);
    {
        int l = idx / (D * D);
        int o = rem / D, c = rem - o * D;
        int no = o >> 4, lo = o & 15, kc = c >> 5, lc = (c >> 3) & 3, jc = c & 7;
        pwS[(size_t)l * D * D + (size_t)(((no * 3 + kc) * 64 + lc * 16 + lo) * 8 + jc)] =
            f2h(cpw[idx]);
    }
    if (idx < 48 * 96) {
        int m = idx / 96, c = idx - m * 96;
        int nm = m >> 4, lm = m & 15, kc = c >> 5, lc = (c >> 3) & 3, jc = c & 7;
        w1S[((nm * 3 + kc) * 64 + lc * 16 + lm) * 8 + jc] = f2h(w1[c * 48 + m]);
    }
    if (idx < 96 * 64) {
        int o = idx / 64, mk = idx - o * 64;
        int no = o >> 4, lo = o & 15, km = mk >> 5, lm2 = (mk >> 3) & 3, jm = mk & 7;
        w2S[((no * 2 + km) * 64 + lm2 * 16 + lo) * 8 + jm] =
            (mk < 48) ? f2h(w2[mk * 96 + o]) : (us)0;
    }
}

// ---------------- WVO_h = WV_h @ WO_h -> fragment order ----------------
__global__ void prep_wvo(const float* __restrict__ WV, const float* __restrict__ WO,
                         us* __restrict__ wvoS) {
    int blk = blockIdx.x;  // 24 = H * 6
    int h = blk / 6, ot = blk - h * 6;
    int tid = threadIdx.x;
    const float* wv = WV + (size_t)h * D * D;
    const float* wo = WO + (size_t)h * D * D;
    for (int i = tid; i < 16 * 96; i += 256) {
        int lmod = i / 96, d = i - (i / 96) * 96;
        int o = ot * 16 + lmod;
        float acc = 0.f;
        for (int e = 0; e < 96; e++) acc += wv[d * 96 + e] * wo[e * 96 + o];
        int kk = d >> 5, ldiv = (d >> 3) & 3, j = d & 7;
        wvoS[(size_t)h * D * D + (size_t)(((ot * 3 + kk) * 64 + ldiv * 16 + lmod) * 8 + j)] =
            f2h(acc);
    }
}

// ---------------- conv0: embed + LN0 (halo inline) + dw + pw + residual + LN1 ----------------
__global__ void conv0f(const float* __restrict__ in, const float* __restrict__ pe,
                       const float* __restrict__ g0, const float* __restrict__ b0,
                       float* __restrict__ xout, us* __restrict__ lnout,
                       const float* __restrict__ dwW, const float* __restrict__ dwB,
                       const us* __restrict__ pwW, const float* __restrict__ pwb,
                       const float* __restrict__ gnext, const float* __restrict__ bnext) {
    __shared__ us lnb_s[70 * 104];
    __shared__ us dwb_s[64 * 104];
    __shared__ float lw[96 * 8];
    int tid = threadIdx.x;
    int wave = tid >> 6, lane = tid & 63;
    int r0 = blockIdx.x * 64;
    int b = r0 / S, s0 = r0 % S;

    for (int i = tid; i < 96 * KW; i += 256) lw[(i / KW) * 8 + (i % KW)] = dwW[i];

    for (int i = wave; i < 70; i += 4) {
        int s = s0 - 3 + i;
        bool valid = (unsigned)s < (unsigned)S;
        float v0 = 0.f, v1 = 0.f;
        if (valid) {
            size_t ro = ((size_t)b * S + s) * 96;
            v0 = in[ro + lane] * SQRTD + pe[s * 96 + lane];
            v1 = (lane < 32) ? in[ro + 64 + lane] * SQRTD + pe[s * 96 + 64 + lane] : 0.f;
        }
        float sm = v0 + v1, q = v0 * v0 + v1 * v1;
        for (int off = 32; off > 0; off >>= 1) {
            sm += __shfl_xor(sm, off);
            q += __shfl_xor(q, off);
        }
        float mean = sm * (1.0f / D);
        float var = q * (1.0f / D) - mean * mean;
        float rstd = rsqrtf(var + 1e-5f);
        lnb_s[i * 104 + lane] = f2h(valid ? (v0 - mean) * rstd * g0[lane] + b0[lane] : 0.f);
        if (lane < 32)
            lnb_s[i * 104 + 64 + lane] =
                f2h(valid ? (v1 - mean) * rstd * g0[lane + 64] + b0[lane + 64] : 0.f);
    }
    __syncthreads();

    for (int u = tid; u < 768; u += 256) {
        int j = u / 12, c0 = (u - (u / 12) * 12) * 8;
        float acc[8];
        #pragma unroll
        for (int j2 = 0; j2 < 8; j2++) acc[j2] = dwB[c0 + j2];
        #pragma unroll
        for (int k = 0; k < KW; k++) {
            f16x8 v = ldh(&lnb_s[(j + k) * 104 + c0]);
            #pragma unroll
            for (int j2 = 0; j2 < 8; j2++) acc[j2] += (float)v[j2] * lw[(c0 + j2) * 8 + k];
        }
        us8 o;
        #pragma unroll
        for (int j2 = 0; j2 < 8; j2++) o[j2] = f2h(acc[j2]);
        *reinterpret_cast<us8*>(&dwb_s[j * 104 + c0]) = o;
    }
    __syncthreads();

    int lmod = lane & 15, ldiv = lane >> 4, m0 = wave * 16;
    f32x4 acc[6] = {};
    #pragma unroll
    for (int kk = 0; kk < 3; kk++) {
        f16x8 af = ldh(&dwb_s[(m0 + lmod) * 104 + kk * 32 + ldiv * 8]);
        #pragma unroll
        for (int n = 0; n < 6; n++) {
            f16x8 bf = ldh(pwW + (size_t)((n * 3 + kk) * 64) * 8 + lane * 8);
            acc[n] = __builtin_amdgcn_mfma_f32_16x16x32_f16(af, bf, acc[n], 0, 0, 0);
        }
    }

    float gv[6], bv2[6], pb[6];
    #pragma unroll
    for (int n = 0; n < 6; n++) {
        int o = n * 16 + lmod;
        gv[n] = gnext[o];
        bv2[n] = bnext[o];
        pb[n] = pwb[o];
    }
    #pragma unroll
    for (int n = 0; n < 6; n++) {
        int o = n * 16 + lmod;
        #pragma unroll
        for (int r = 0; r < 4; r++) {
            int sr = m0 + ldiv * 4 + r;
            size_t row = (size_t)r0 + sr;
            float base = in[row * 96 + o] * SQRTD + pe[(s0 + sr) * 96 + o];
            acc[n][r] = base + fmaxf(acc[n][r] + pb[n], 0.f);
        }
    }
    #pragma unroll
    for (int r = 0; r < 4; r++) {
        float sm = 0.f, qq = 0.f;
        #pragma unroll
        for (int n = 0; n < 6; n++) {
            sm += acc[n][r];
            qq += acc[n][r] * acc[n][r];
        }
        #pragma unroll
        for (int st = 1; st <= 8; st <<= 1) {
            sm += __shfl_xor(sm, st);
            qq += __shfl_xor(qq, st);
        }
        float mean = sm * (1.0f / D);
        float var = qq * (1.0f / D) - mean * mean;
        float rstd = rsqrtf(var + 1e-5f);
        size_t row = (size_t)r0 + m0 + ldiv * 4 + r;
        #pragma unroll
        for (int n = 0; n < 6; n++) {
            int o = n * 16 + lmod;
            xout[row * 96 + o] = acc[n][r];
            lnout[row * 96 + o] = f2h((acc[n][r] - mean) * rstd * gv[n] + bv2[n]);
        }
    }
}

// ---------------- mid conv layer ----------------
__global__ void conv2(const float* __restrict__ xin, const us* __restrict__ lnin,
                      float* __restrict__ xout, us* __restrict__ lnout,
                      const float* __restrict__ dwW, const float* __restrict__ dwB,
                      const us* __restrict__ pwW, const float* __restrict__ pwb,
                      const float* __restrict__ gnext, const float* __restrict__ bnext) {
    __shared__ us dwb_s[64 * 104];
    __shared__ float lw[96 * 8];
    int tid = threadIdx.x;
    int wave = tid >> 6, lane = tid & 63;
    int r0 = blockIdx.x * 64;
    int b = r0 / S, s0 = r0 % S;

    for (int i = tid; i < 96 * KW; i += 256) lw[(i / KW) * 8 + (i % KW)] = dwW[i];
    __syncthreads();

    for (int u = tid; u < 768; u += 256) {
        int j = u / 12, c0 = (u - (u / 12) * 12) * 8;
        float acc[8];
        #pragma unroll
        for (int j2 = 0; j2 < 8; j2++) acc[j2] = dwB[c0 + j2];
        #pragma unroll
        for (int k = 0; k < KW; k++) {
            int ss = s0 + j + k - 3;
            if ((unsigned)ss < (unsigned)S) {
                f16x8 v = ldh(lnin + ((size_t)b * S + ss) * 96 + c0);
                #pragma unroll
                for (int j2 = 0; j2 < 8; j2++) acc[j2] += (float)v[j2] * lw[(c0 + j2) * 8 + k];
            }
        }
        us8 o;
        #pragma unroll
        for (int j2 = 0; j2 < 8; j2++) o[j2] = f2h(acc[j2]);
        *reinterpret_cast<us8*>(&dwb_s[j * 104 + c0]) = o;
    }
    __syncthreads();

    int lmod = lane & 15, ldiv = lane >> 4, m0 = wave * 16;
    f32x4 acc[6] = {};
    #pragma unroll
    for (int kk = 0; kk < 3; kk++) {
        f16x8 af = ldh(&dwb_s[(m0 + lmod) * 104 + kk * 32 + ldiv * 8]);
        #pragma unroll
        for (int n = 0; n < 6; n++) {
            f16x8 bf = ldh(pwW + (size_t)((n * 3 + kk) * 64) * 8 + lane * 8);
            acc[n] = __builtin_amdgcn_mfma_f32_16x16x32_f16(af, bf, acc[n], 0, 0, 0);
        }
    }

    float gv[6], bv2[6], pb[6];
    #pragma unroll
    for (int n = 0; n < 6; n++) {
        int o = n * 16 + lmod;
        gv[n] = gnext[o];
        bv2[n] = bnext[o];
        pb[n] = pwb[o];
    }
    #pragma unroll
    for (int n = 0; n < 6; n++) {
        #pragma unroll
        for (int r = 0; r < 4; r++) {
            size_t row = (size_t)r0 + m0 + ldiv * 4 + r;
            acc[n][r] = xin[row * 96 + n * 16 + lmod] + fmaxf(acc[n][r] + pb[n], 0.f);
        }
    }
    #pragma unroll
    for (int r = 0; r < 4; r++) {
        float sm = 0.f, qq = 0.f;
        #pragma unroll
        for (int n = 0; n < 6; n++) {
            sm += acc[n][r];
            qq += acc[n][r] * acc[n][r];
        }
        #pragma unroll
        for (int st = 1; st <= 8; st <<= 1) {
            sm += __shfl_xor(sm, st);
            qq += __shfl_xor(qq, st);
        }
        float mean = sm * (1.0f / D);
        float var = qq * (1.0f / D) - mean * mean;
        float rstd = rsqrtf(var + 1e-5f);
        size_t row = (size_t)r0 + m0 + ldiv * 4 + r;
        #pragma unroll
        for (int n = 0; n < 6; n++) {
            int o = n * 16 + lmod;
            xout[row * 96 + o] = acc[n][r];
            lnout[row * 96 + o] = f2h((acc[n][r] - mean) * rstd * gv[n] + bv2[n]);
        }
    }
}

// ---------------- conv3 + K/V' projection fused (V 64-key-chunk layout) ----------------
__global__ void conv3p(const float* __restrict__ xin, const us* __restrict__ lnin,
                       float* __restrict__ xout, us* __restrict__ lnout,
                       const float* __restrict__ dwW, const float* __restrict__ dwB,
                       const us* __restrict__ pwW, const float* __restrict__ pwb,
                       const float* __restrict__ gnext, const float* __restrict__ bnext,
                       const us* __restrict__ wkS, const us* __restrict__ wvoS,
                       us* __restrict__ Kall, us* __restrict__ Vall) {
    __shared__ float lw[96 * 8];
    __shared__ us stg[96 * 72];
    __shared__ us lnstg[64 * 104];
    int tid = threadIdx.x;
    int wave = tid >> 6, lane = tid & 63;
    int lmod = lane & 15, ldiv = lane >> 4, m0 = wave * 16;
    int r0 = blockIdx.x * 64;
    int b = r0 / S, s0 = r0 % S;

    for (int i = tid; i < 96 * KW; i += 256) lw[(i / KW) * 8 + (i % KW)] = dwW[i];
    __syncthreads();

    for (int u = tid; u < 768; u += 256) {
        int j = u / 12, c0 = (u - (u / 12) * 12) * 8;
        float acc[8];
        #pragma unroll
        for (int j2 = 0; j2 < 8; j2++) acc[j2] = dwB[c0 + j2];
        #pragma unroll
        for (int k = 0; k < KW; k++) {
            int ss = s0 + j + k - 3;
            if ((unsigned)ss < (unsigned)S) {
                f16x8 v = ldh(lnin + ((size_t)b * S + ss) * 96 + c0);
                #pragma unroll
                for (int j2 = 0; j2 < 8; j2++) acc[j2] += (float)v[j2] * lw[(c0 + j2) * 8 + k];
            }
        }
        us8 o;
        #pragma unroll
        for (int j2 = 0; j2 < 8; j2++) o[j2] = f2h(acc[j2]);
        *reinterpret_cast<us8*>(&stg[j * 104 + c0]) = o;
    }
    __syncthreads();

    f32x4 acc[6] = {};
    #pragma unroll
    for (int kk = 0; kk < 3; kk++) {
        f16x8 af = ldh(&stg[(m0 + lmod) * 104 + kk * 32 + ldiv * 8]);
        #pragma unroll
        for (int n = 0; n < 6; n++) {
            f16x8 bf = ldh(pwW + (size_t)((n * 3 + kk) * 64) * 8 + lane * 8);
            acc[n] = __builtin_amdgcn_mfma_f32_16x16x32_f16(af, bf, acc[n], 0, 0, 0);
        }
    }

    float gv[6], bv2[6], pb[6];
    #pragma unroll
    for (int n = 0; n < 6; n++) {
        int o = n * 16 + lmod;
        gv[n] = gnext[o];
        bv2[n] = bnext[o];
        pb[n] = pwb[o];
    }
    #pragma unroll
    for (int n = 0; n < 6; n++) {
        #pragma unroll
        for (int r = 0; r < 4; r++) {
            size_t row = (size_t)r0 + m0 + ldiv * 4 + r;
            acc[n][r] = xin[row * 96 + n * 16 + lmod] + fmaxf(acc[n][r] + pb[n], 0.f);
        }
    }
    #pragma unroll
    for (int r = 0; r < 4; r++) {
        float sm = 0.f, qq = 0.f;
        #pragma unroll
        for (int n = 0; n < 6; n++) {
            sm += acc[n][r];
            qq += acc[n][r] * acc[n][r];
        }
        #pragma unroll
        for (int st = 1; st <= 8; st <<= 1) {
            sm += __shfl_xor(sm, st);
            qq += __shfl_xor(qq, st);
        }
        float mean = sm * (1.0f / D);
        float var = qq * (1.0f / D) - mean * mean;
        float rstd = rsqrtf(var + 1e-5f);
        size_t row = (size_t)r0 + m0 + ldiv * 4 + r;
        #pragma unroll
        for (int n = 0; n < 6; n++) {
            int o = n * 16 + lmod;
            xout[row * 96 + o] = acc[n][r];
            us hv = f2h((acc[n][r] - mean) * rstd * gv[n] + bv2[n]);
            lnout[row * 96 + o] = hv;
            lnstg[(m0 + ldiv * 4 + r) * 104 + o] = hv;
        }
    }
    __syncthreads();

    f16x8 af[3];
    #pragma unroll
    for (int kk = 0; kk < 3; kk++)
        af[kk] = ldh(&lnstg[(m0 + lmod) * 104 + kk * 32 + ldiv * 8]);

    for (int hd = 0; hd < H; hd++) {
        // ---- K ----
        f32x4 ka[6] = {};
        #pragma unroll
        for (int kk = 0; kk < 3; kk++)
            #pragma unroll
            for (int n = 0; n < 6; n++) {
                f16x8 bf = ldh(wkS + (size_t)hd * D * D + (size_t)((n * 3 + kk) * 64) * 8 + lane * 8);
                ka[n] = __builtin_amdgcn_mfma_f32_16x16x32_f16(af[kk], bf, ka[n], 0, 0, 0);
            }
        __syncthreads();
        us* kT = stg + wave * 1664;
        #pragma unroll
        for (int n = 0; n < 6; n++)
            #pragma unroll
            for (int r = 0; r < 4; r++)
                kT[(ldiv * 4 + r) * 104 + n * 16 + lmod] = f2h(ka[n][r]);
        int t0 = (r0 % S) / 16 + wave;
        us* dst = Kall + (size_t)hd * NTOT + ((size_t)(b * 24 + t0) * 3) * 512;
        #pragma unroll
        for (int kk = 0; kk < 3; kk++) {
            us8 v = *reinterpret_cast<const us8*>(&kT[lmod * 104 + kk * 32 + ldiv * 8]);
            *reinterpret_cast<us8*>(dst + kk * 512 + lane * 8) = v;
        }
        // ---- V' ---- 64-key-chunk layout: [b][cblk(6)][n(6)][kk(2)][512]
        f32x4 va[6] = {};
        #pragma unroll
        for (int kk = 0; kk < 3; kk++)
            #pragma unroll
            for (int n = 0; n < 6; n++) {
                f16x8 bf =
                    ldh(wvoS + (size_t)hd * D * D + (size_t)((n * 3 + kk) * 64) * 8 + lane * 8);
                va[n] = __builtin_amdgcn_mfma_f32_16x16x32_f16(af[kk], bf, va[n], 0, 0, 0);
            }
        __syncthreads();
        #pragma unroll
        for (int n = 0; n < 6; n++)
            #pragma unroll
            for (int r = 0; r < 4; r++)
                stg[(n * 16 + lmod) * 72 + m0 + ldiv * 4 + r] = f2h(va[n][r]);
        __syncthreads();
        int cblk = (r0 % S) / 64;
        us* dsth = Vall + (size_t)hd * NTOT;
        #pragma unroll
        for (int n = 0; n < 6; n++)
            #pragma unroll
            for (int kk = 0; kk < 2; kk++) {
                us8 v =
                    *reinterpret_cast<const us8*>(&stg[(n * 16 + lmod) * 72 + kk * 32 + ldiv * 8]);
                *reinterpret_cast<us8*>(
                    dsth + ((size_t)((b * 6 + cblk) * 6 + n) * 2 + kk) * 512 + lane * 8) = v;
            }
    }
}

// ---------------- block-cooperative LDS-staged attention, swapped QK^T ----------------
// grid 1024 = 128 b x 4 hd x 2 qhalf; 4 waves x 48 q-rows; 64-key chunks, K/V dbuf.
__global__ __launch_bounds__(256, 2) void attn_g(const us* __restrict__ h16,
                                                 const us* __restrict__ wqS,
                                                 const us* __restrict__ Kall,
                                                 const us* __restrict__ Vall,
                                                 us* __restrict__ xpart) {
    __shared__ us pool[38400];  // Kb:0/6144 | Vb:12288/18432 | P:24576+wave*3456 ; prologue Qstage: wave*4992
    int tid = threadIdx.x, wave = tid >> 6, lane = tid & 63;
    int lmod = lane & 15, ldiv = lane >> 4;
    int p = blockIdx.x;
    int gl = (p & 7) * 128 + (p >> 3);  // XCD swizzle, 1024 = 8*128
    int qt = gl & 1;
    int bh = gl >> 1;
    int b = bh >> 2, hd = bh & 3;
    size_t rowbase = (size_t)b * S + qt * 192 + wave * 48;

    const us* Kh = Kall + (size_t)hd * NTOT + (size_t)b * 24 * 1536;
    const us* Vh = Vall + (size_t)hd * NTOT + (size_t)b * 36 * 1024;
    us* P = pool + 24576 + wave * 3456;  // [48][72]

    // prologue: issue K0 staging loads; Q-proj under their latency
    us8 k0s[3];
    #pragma unroll
    for (int j = 0; j < 3; j++)
        k0s[j] = *reinterpret_cast<const us8*>(Kh + (size_t)(j * 256 + tid) * 8);

    f32x4 qa0[6] = {}, qa1[6] = {}, qa2[6] = {};
    #pragma unroll
    for (int kk = 0; kk < 3; kk++) {
        f16x8 a0 = ldh(h16 + (rowbase + lmod) * 96 + kk * 32 + ldiv * 8);
        f16x8 a1 = ldh(h16 + (rowbase + 16 + lmod) * 96 + kk * 32 + ldiv * 8);
        f16x8 a2 = ldh(h16 + (rowbase + 32 + lmod) * 96 + kk * 32 + ldiv * 8);
        #pragma unroll
        for (int n = 0; n < 6; n++) {
            f16x8 bf = ldh(wqS + (size_t)hd * D * D + (size_t)((n * 3 + kk) * 64) * 8 + lane * 8);
            qa0[n] = __builtin_amdgcn_mfma_f32_16x16x32_f16(a0, bf, qa0[n], 0, 0, 0);
            qa1[n] = __builtin_amdgcn_mfma_f32_16x16x32_f16(a1, bf, qa1[n], 0, 0, 0);
            qa2[n] = __builtin_amdgcn_mfma_f32_16x16x32_f16(a2, bf, qa2[n], 0, 0, 0);
        }
    }
    us* qst = pool + wave * 4992;  // [48][104], wave-private (overlaps Kb/Vb; barrier below)
    #pragma unroll
    for (int n = 0; n < 6; n++)
        #pragma unroll
        for (int r = 0; r < 4; r++) {
            qst[(ldiv * 4 + r) * 104 + n * 16 + lmod] = f2h(qa0[n][r]);
            qst[(16 + ldiv * 4 + r) * 104 + n * 16 + lmod] = f2h(qa1[n][r]);
            qst[(32 + ldiv * 4 + r) * 104 + n * 16 + lmod] = f2h(qa2[n][r]);
        }
    f16x8 aq0[3], aq1[3], aq2[3];
    #pragma unroll
    for (int kk = 0; kk < 3; kk++) {
        aq0[kk] = ldh(&qst[lmod * 104 + kk * 32 + ldiv * 8]);
        aq1[kk] = ldh(&qst[(16 + lmod) * 104 + kk * 32 + ldiv * 8]);
        aq2[kk] = ldh(&qst[(32 + lmod) * 104 + kk * 32 + ldiv * 8]);
    }
    __syncthreads();  // all waves done with Q staging in pool
    #pragma unroll
    for (int j = 0; j < 3; j++)
        *reinterpret_cast<us8*>(&pool[(j * 256 + tid) * 8]) = k0s[j];
    __syncthreads();

    // ---- pass 1: row max (swapped mfma(K,Q): lane lmod = q-row, regs = k) ----
    float mx0 = -1e30f, mx1 = -1e30f, mx2 = -1e30f;
    for (int c = 0; c < 6; c++) {
        us* kbc = pool + (c & 1) * 6144;
        us8 kn[3], vn[3];
        bool last = (c == 5);
        if (!last) {
            const us* src = Kh + (size_t)(c + 1) * 6144;
            #pragma unroll
            for (int j = 0; j < 3; j++)
                kn[j] = *reinterpret_cast<const us8*>(src + (size_t)(j * 256 + tid) * 8);
        } else {
            #pragma unroll
            for (int j = 0; j < 3; j++) {
                kn[j] = *reinterpret_cast<const us8*>(Kh + (size_t)(j * 256 + tid) * 8);
                vn[j] = *reinterpret_cast<const us8*>(Vh + (size_t)(j * 256 + tid) * 8);
            }
        }
        __builtin_amdgcn_s_setprio(1);
        f32x4 s0[4] = {}, s1[4] = {}, s2[4] = {};
        #pragma unroll
        for (int nt = 0; nt < 4; nt++)
            #pragma unroll
            for (int kk = 0; kk < 3; kk++) {
                f16x8 bf = ldh(&kbc[(nt * 3 + kk) * 512 + lane * 8]);
                s0[nt] = __builtin_amdgcn_mfma_f32_16x16x32_f16(bf, aq0[kk], s0[nt], 0, 0, 0);
                s1[nt] = __builtin_amdgcn_mfma_f32_16x16x32_f16(bf, aq1[kk], s1[nt], 0, 0, 0);
                s2[nt] = __builtin_amdgcn_mfma_f32_16x16x32_f16(bf, aq2[kk], s2[nt], 0, 0, 0);
            }
        __builtin_amdgcn_s_setprio(0);
        #pragma unroll
        for (int nt = 0; nt < 4; nt++)
            #pragma unroll
            for (int r = 0; r < 4; r++) {
                mx0 = fmaxf(mx0, s0[nt][r]);
                mx1 = fmaxf(mx1, s1[nt][r]);
                mx2 = fmaxf(mx2, s2[nt][r]);
            }
        us* kbw = pool + (last ? 0 : ((c & 1) ^ 1)) * 6144;
        #pragma unroll
        for (int j = 0; j < 3; j++)
            *reinterpret_cast<us8*>(&kbw[(j * 256 + tid) * 8]) = kn[j];
        if (last) {
            #pragma unroll
            for (int j = 0; j < 3; j++)
                *reinterpret_cast<us8*>(&pool[12288 + (j * 256 + tid) * 8]) = vn[j];
        }
        __syncthreads();
    }
    mx0 = fmaxf(mx0, __shfl_xor(mx0, 16));
    mx0 = fmaxf(mx0, __shfl_xor(mx0, 32));
    mx1 = fmaxf(mx1, __shfl_xor(mx1, 16));
    mx1 = fmaxf(mx1, __shfl_xor(mx1, 32));
    mx2 = fmaxf(mx2, __shfl_xor(mx2, 16));
    mx2 = fmaxf(mx2, __shfl_xor(mx2, 32));

    // ---- pass 2: scores (swapped) -> exp2 -> packed P write -> PV ----
    f32x4 oacc0[6] = {}, oacc1[6] = {}, oacc2[6] = {};
    float l0 = 0.f, l1 = 0.f, l2 = 0.f;
    for (int c = 0; c < 6; c++) {
        us* kbc = pool + (c & 1) * 6144;
        us* vbc = pool + 12288 + (c & 1) * 6144;
        us8 kn[3], vn[3];
        if (c < 5) {
            const us* ksrc = Kh + (size_t)(c + 1) * 6144;
            const us* vsrc = Vh + (size_t)(c + 1) * 6144;
            #pragma unroll
            for (int j = 0; j < 3; j++) {
                kn[j] = *reinterpret_cast<const us8*>(ksrc + (size_t)(j * 256 + tid) * 8);
                vn[j] = *reinterpret_cast<const us8*>(vsrc + (size_t)(j * 256 + tid) * 8);
            }
        }
        __builtin_amdgcn_s_setprio(1);
        f32x4 s0[4] = {}, s1[4] = {}, s2[4] = {};
        #pragma unroll
        for (int nt = 0; nt < 4; nt++)
            #pragma unroll
            for (int kk = 0; kk < 3; kk++) {
                f16x8 bf = ldh(&kbc[(nt * 3 + kk) * 512 + lane * 8]);
                s0[nt] = __builtin_amdgcn_mfma_f32_16x16x32_f16(bf, aq0[kk], s0[nt], 0, 0, 0);
                s1[nt] = __builtin_amdgcn_mfma_f32_16x16x32_f16(bf, aq1[kk], s1[nt], 0, 0, 0);
                s2[nt] = __builtin_amdgcn_mfma_f32_16x16x32_f16(bf, aq2[kk], s2[nt], 0, 0, 0);
            }
        __builtin_amdgcn_s_setprio(0);
        // exp2 + packed b64 P writes (row = m*16+lmod, k = nt*16+ldiv*4+r)
        #pragma unroll
        for (int nt = 0; nt < 4; nt++) {
            us4 pk0, pk1, pk2;
            #pragma unroll
            for (int r = 0; r < 4; r++) {
                float p0 = exp2f(s0[nt][r] - mx0);
                float p1 = exp2f(s1[nt][r] - mx1);
                float p2 = exp2f(s2[nt][r] - mx2);
                l0 += p0;
                l1 += p1;
                l2 += p2;
                pk0[r] = f2h(p0);
                pk1[r] = f2h(p1);
                pk2[r] = f2h(p2);
            }
            int kc = nt * 16 + ldiv * 4;
            *reinterpret_cast<us4*>(&P[lmod * 72 + kc]) = pk0;
            *reinterpret_cast<us4*>(&P[(16 + lmod) * 72 + kc]) = pk1;
            *reinterpret_cast<us4*>(&P[(32 + lmod) * 72 + kc]) = pk2;
        }
        __builtin_amdgcn_s_setprio(1);
        #pragma unroll
        for (int kk = 0; kk < 2; kk++) {
            f16x8 pf0 = ldh(&P[lmod * 72 + kk * 32 + ldiv * 8]);
            f16x8 pf1 = ldh(&P[(16 + lmod) * 72 + kk * 32 + ldiv * 8]);
            f16x8 pf2 = ldh(&P[(32 + lmod) * 72 + kk * 32 + ldiv * 8]);
            #pragma unroll
            for (int n = 0; n < 6; n++) {
                f16x8 bf = ldh(&vbc[(n * 2 + kk) * 512 + lane * 8]);
                oacc0[n] = __builtin_amdgcn_mfma_f32_16x16x32_f16(pf0, bf, oacc0[n], 0, 0, 0);
                oacc1[n] = __builtin_amdgcn_mfma_f32_16x16x32_f16(pf1, bf, oacc1[n], 0, 0, 0);
                oacc2[n] = __builtin_amdgcn_mfma_f32_16x16x32_f16(pf2, bf, oacc2[n], 0, 0, 0);
            }
        }
        __builtin_amdgcn_s_setprio(0);
        if (c < 5) {
            us* kbn = pool + ((c & 1) ^ 1) * 6144;
            us* vbn = pool + 12288 + ((c & 1) ^ 1) * 6144;
            #pragma unroll
            for (int j = 0; j < 3; j++) {
                *reinterpret_cast<us8*>(&kbn[(j * 256 + tid) * 8]) = kn[j];
                *reinterpret_cast<us8*>(&vbn[(j * 256 + tid) * 8]) = vn[j];
            }
            __syncthreads();
        }
    }
    l0 += __shfl_xor(l0, 16);
    l0 += __shfl_xor(l0, 32);
    l1 += __shfl_xor(l1, 16);
    l1 += __shfl_xor(l1, 32);
    l2 += __shfl_xor(l2, 16);
    l2 += __shfl_xor(l2, 32);

    // epilogue: l lives at lane lmod=q; oacc rows are q=ldiv*4+r -> shuffle redistribute
    us* xp = xpart + (size_t)hd * NTOT;
    #pragma unroll
    for (int r = 0; r < 4; r++) {
        int srcl = ldiv * 4 + r;  // lane < 16 has lmod == srcl
        float inv0 = 1.f / __shfl(l0, srcl);
        float inv1 = 1.f / __shfl(l1, srcl);
        float inv2 = 1.f / __shfl(l2, srcl);
        #pragma unroll
        for (int n = 0; n < 6; n++) {
            xp[(rowbase + ldiv * 4 + r) * 96 + n * 16 + lmod] = f2h(oacc0[n][r] * inv0);
            xp[(rowbase + 16 + ldiv * 4 + r) * 96 + n * 16 + lmod] = f2h(oacc1[n][r] * inv1);
            xp[(rowbase + 32 + ldiv * 4 + r) * 96 + n * 16 + lmod] = f2h(oacc2[n][r] * inv2);
        }
    }
}

// ---------------- fused head-reduce + LN + FFN ----------------
__global__ void ffn_ln(const float* __restrict__ x, const us* __restrict__ xpart,
                       const float* __restrict__ gln, const float* __restrict__ bln,
                       const us* __restrict__ w1S, const float* __restrict__ b1,
                       const us* __restrict__ w2S, const float* __restrict__ b2,
                       float* __restrict__ out) {
    __shared__ float xf[64 * 96];
    __shared__ us lnb[64 * 104];
    __shared__ us mid[64 * 72];
    int tid = threadIdx.x, wave = tid >> 6, lane = tid & 63;
    int lmod = lane & 15, ldiv = lane >> 4, m0 = wave * 16;
    int row0 = blockIdx.x * 64;

    for (int i = wave; i < 64; i += 4) {
        size_t ro = (size_t)(row0 + i) * 96;
        float v0 = x[ro + lane];
        float v1 = (lane < 32) ? x[ro + 64 + lane] : 0.f;
        #pragma unroll
        for (int h = 0; h < H; h++) {
            const us* xp = xpart + (size_t)h * NTOT + ro;
            v0 += (float)__builtin_bit_cast(_Float16, xp[lane]);
            if (lane < 32) v1 += (float)__builtin_bit_cast(_Float16, xp[64 + lane]);
        }
        xf[i * 96 + lane] = v0;
        if (lane < 32) xf[i * 96 + 64 + lane] = v1;
        float sm = v0 + v1, q = v0 * v0 + v1 * v1;
        for (int off = 32; off > 0; off >>= 1) {
            sm += __shfl_xor(sm, off);
            q += __shfl_xor(q, off);
        }
        float mean = sm * (1.0f / D);
        float var = q * (1.0f / D) - mean * mean;
        float rstd = rsqrtf(var + 1e-5f);
        lnb[i * 104 + lane] = f2h((v0 - mean) * rstd * gln[lane] + bln[lane]);
        if (lane < 32)
            lnb[i * 104 + 64 + lane] = f2h((v1 - mean) * rstd * gln[lane + 64] + bln[lane + 64]);
    }
    __syncthreads();

    f32x4 a3[3] = {};
    #pragma unroll
    for (int kk = 0; kk < 3; kk++) {
        f16x8 af = ldh(&lnb[(m0 + lmod) * 104 + kk * 32 + ldiv * 8]);
        #pragma unroll
        for (int n = 0; n < 3; n++) {
            f16x8 bf = ldh(w1S + (size_t)((n * 3 + kk) * 64) * 8 + lane * 8);
            a3[n] = __builtin_amdgcn_mfma_f32_16x16x32_f16(af, bf, a3[n], 0, 0, 0);
        }
    }
    #pragma unroll
    for (int n = 0; n < 3; n++) {
        float bv = b1[n * 16 + lmod];
        #pragma unroll
        for (int r = 0; r < 4; r++) {
            float v = a3[n][r] + bv;
            mid[(m0 + ldiv * 4 + r) * 72 + n * 16 + lmod] = f2h(1.f / (1.f + __expf(-v)));
        }
    }
    #pragma unroll
    for (int r = 0; r < 4; r++) mid[(m0 + ldiv * 4 + r) * 72 + 48 + lmod] = 0;
    __syncthreads();

    f32x4 a6[6] = {};
    #pragma unroll
    for (int kk = 0; kk < 2; kk++) {
        f16x8 af = ldh(&mid[(m0 + lmod) * 72 + kk * 32 + ldiv * 8]);
        #pragma unroll
        for (int n = 0; n < 6; n++) {
            f16x8 bf = ldh(w2S + (size_t)((n * 2 + kk) * 64) * 8 + lane * 8);
            a6[n] = __builtin_amdgcn_mfma_f32_16x16x32_f16(af, bf, a6[n], 0, 0, 0);
        }
    }
    #pragma unroll
    for (int n = 0; n < 6; n++) {
        int o = n * 16 + lmod;
        float bv = b2[o];
        #pragma unroll
        for (int r = 0; r < 4; r++) {
            int sr = m0 + ldiv * 4 + r;
            out[(size_t)(row0 + sr) * 96 + o] = xf[sr * 96 + o] + a6[n][r] + bv;
        }
    }
}

extern "C" void kernel_launch(void* const* d_in, const int* in_sizes, int n_in,
                              void* d_out, int out_size, void* d_ws, size_t ws_size,
                              hipStream_t stream) {
    const float* in   = (const float*)d_in[0];
    const float* cdw  = (const float*)d_in[2];
    const float* cdwb = (const float*)d_in[3];
    const float* cpw  = (const float*)d_in[4];
    const float* cpwb = (const float*)d_in[5];
    const float* WQ   = (const float*)d_in[6];
    const float* WK   = (const float*)d_in[7];
    const float* WV   = (const float*)d_in[8];
    const float* WO   = (const float*)d_in[9];
    const float* w1   = (const float*)d_in[10];
    const float* b1   = (const float*)d_in[11];
    const float* w2   = (const float*)d_in[12];
    const float* b2   = (const float*)d_in[13];
    const float* lng  = (const float*)d_in[14];
    const float* lnb  = (const float*)d_in[15];
    float* out = (float*)d_out;
    float* ws = (float*)d_ws;

    float* xA  = ws;
    float* xB  = xA + NTOT;
    float* pe  = xB + NTOT;
    us* lnA    = (us*)(pe + S * D);
    us* lnB    = lnA + NTOT;
    us* Kall   = lnB + NTOT;               // [H][B][24][3][64][8]
    us* Vall   = Kall + (size_t)H * NTOT;  // [H][B][6 cblk][6 n][2 kk][512]
    us* xpart  = Vall + (size_t)H * NTOT;  // [H][ROWS][96]
    us* wqS    = xpart + (size_t)H * NTOT;
    us* wkS    = wqS + H * D * D;
    us* wvoS   = wkS + H * D * D;
    us* pwS    = wvoS + H * D * D;
    us* w1S    = pwS + L * D * D;
    us* w2S    = w1S + 48 * 96;
    // total ~= 170 MB (< 256 MB ws)

    pe_kernel<<<(S * D + 255) / 256, 256, 0, stream>>>(pe);
    prep_w<<<(H * D * D + 255) / 256, 256, 0, stream>>>(WQ, WK, cpw, w1, w2,
                                                        wqS, wkS, pwS, w1S, w2S);
    prep_wvo<<<H * 6, 256, 0, stream>>>(WV, WO, wvoS);

    conv0f<<<ROWS / 64, 256, 0, stream>>>(in, pe, lng, lnb, xA, lnB,
                                          cdw, cdwb, pwS, cpwb, lng + D, lnb + D);
    conv2<<<ROWS / 64, 256, 0, stream>>>(xA, lnB, xB, lnA, cdw + D * KW, cdwb + D,
                                         pwS + D * D, cpwb + D, lng + 2 * D, lnb + 2 * D);
    conv2<<<ROWS / 64, 256, 0, stream>>>(xB, lnA, xA, lnB, cdw + 2 * D * KW, cdwb + 2 * D,
                                         pwS + 2 * D * D, cpwb + 2 * D, lng + 3 * D,
                                         lnb + 3 * D);
    conv3p<<<ROWS / 64, 256, 0, stream>>>(xA, lnB, xB, lnA, cdw + 3 * D * KW, cdwb + 3 * D,
                                          pwS + 3 * D * D, cpwb + 3 * D, lng + 4 * D,
                                          lnb + 4 * D, wkS, wvoS, Kall, Vall);

    // lnA == h16, xB == x4
    attn_g<<<1024, 256, 0, stream>>>(lnA, wqS, Kall, Vall, xpart);

    ffn_ln<<<ROWS / 64, 256, 0, stream>>>(xB, xpart, lng + 5 * D, lnb + 5 * D,
                                          w1S, b1, w2S, b2, out);
}

// Round 24
// 272.789 us; speedup vs baseline: 1.0441x; 1.0068x over previous
//
#include <hip/hip_runtime.h>
#include <math.h>

// EmbeddingEncoder: B=128, S=384, D=96, H=4, K=7, L=4.
// Round 24: ONE-PASS online-softmax attention on the swapped-QK^T layout
// (r23). Scalar running max/sum per lane (q=lmod) -> cheap rescale (no trees).
// Deletes pass-1 recompute: -216 MFMAs/wave, -72 ds_reads, -6 barriers, K
// fetched once. Rest identical to r23 (274.6 us, absmax 0.25).

constexpr int B = 128;
constexpr int S = 384;
constexpr int D = 96;
constexpr int H = 4;
constexpr int KW = 7;
constexpr int L = 4;
constexpr int ROWS = B * S;                      // 49152
constexpr long long NTOT = (long long)ROWS * D;  // 4718592
constexpr float SQRTD = 9.797958971132712f;
constexpr float LOG2E = 1.4426950408889634f;

typedef _Float16 f16x8 __attribute__((ext_vector_type(8)));
typedef float f32x4 __attribute__((ext_vector_type(4)));
typedef unsigned short us;
typedef unsigned short us4 __attribute__((ext_vector_type(4)));
typedef unsigned short us8 __attribute__((ext_vector_type(8)));

__device__ __forceinline__ us f2h(float f) {
    _Float16 h = (_Float16)f;
    return __builtin_bit_cast(us, h);
}
__device__ __forceinline__ f16x8 ldh(const us* p) {
    return *reinterpret_cast<const f16x8*>(p);
}

// ---------------- positional encoding ----------------
__global__ void pe_kernel(float* __restrict__ pe) {
    int idx = blockIdx.x * 256 + threadIdx.x;
    if (idx >= S * D) return;
    int s = idx / D, c = idx - s * D;
    int j = c >> 1;
    float expo = (c & 1) ? (4.0f * j + 2.0f) / 96.0f : (4.0f * j) / 96.0f;
    float freq = expf(-expo * logf(10000.0f));
    float ang = (float)s * freq;
    pe[idx] = (c & 1) ? cosf(ang) : sinf(ang);
}

// ---------------- weight prep (ALL weights to fragment order) ----------------
__global__ void prep_w(const float* __restrict__ WQ, const float* __restrict__ WK,
                       const float* __restrict__ cpw, const float* __restrict__ w1,
                       const float* __restrict__ w2,
                       us* __restrict__ wqS, us* __restrict__ wkS, us* __restrict__ pwS,
                       us* __restrict__ w1S, us* __restrict__ w2S) {
    int idx = blockIdx.x * 256 + threadIdx.x;
    if (idx >= H * D * D) return;  // 36864
    int h = idx / (D * D), rem = idx - h * (D * D);
    int d = rem / D, e = rem - d * D;
    int n = e >> 4, lmod = e & 15, kk = d >> 5, ldiv = (d >> 3) & 3, j = d & 7;
    size_t fi = (size_t)(((n * 3 + kk) * 64 + ldiv * 16 + lmod) * 8 + j);
    wqS[(size_t)h * D * D + fi] = f2h(WQ[idx] * SQRTD * LOG2E);
    wkS[(size_t)h * D * D + fi] = f2h(WK[idx]);
    {
        int l = idx / (D * D);
        int o = rem / D, c = rem - o * D;
        int no = o >> 4, lo = o & 15, kc = c >> 5, lc = (c >> 3) & 3, jc = c & 7;
        pwS[(size_t)l * D * D + (size_t)(((no * 3 + kc) * 64 + lc * 16 + lo) * 8 + jc)] =
            f2h(cpw[idx]);
    }
    if (idx < 48 * 96) {
        int m = idx / 96, c = idx - m * 96;
        int nm = m >> 4, lm = m & 15, kc = c >> 5, lc = (c >> 3) & 3, jc = c & 7;
        w1S[((nm * 3 + kc) * 64 + lc * 16 + lm) * 8 + jc] = f2h(w1[c * 48 + m]);
    }
    if (idx < 96 * 64) {
        int o = idx / 64, mk = idx - o * 64;
        int no = o >> 4, lo = o & 15, km = mk >> 5, lm2 = (mk >> 3) & 3, jm = mk & 7;
        w2S[((no * 2 + km) * 64 + lm2 * 16 + lo) * 8 + jm] =
            (mk < 48) ? f2h(w2[mk * 96 + o]) : (us)0;
    }
}

// ---------------- WVO_h = WV_h @ WO_h -> fragment order ----------------
__global__ void prep_wvo(const float* __restrict__ WV, const float* __restrict__ WO,
                         us* __restrict__ wvoS) {
    int blk = blockIdx.x;  // 24 = H * 6
    int h = blk / 6, ot = blk - h * 6;
    int tid = threadIdx.x;
    const float* wv = WV + (size_t)h * D * D;
    const float* wo = WO + (size_t)h * D * D;
    for (int i = tid; i < 16 * 96; i += 256) {
        int lmod = i / 96, d = i - (i / 96) * 96;
        int o = ot * 16 + lmod;
        float acc = 0.f;
        for (int e = 0; e < 96; e++) acc += wv[d * 96 + e] * wo[e * 96 + o];
        int kk = d >> 5, ldiv = (d >> 3) & 3, j = d & 7;
        wvoS[(size_t)h * D * D + (size_t)(((ot * 3 + kk) * 64 + ldiv * 16 + lmod) * 8 + j)] =
            f2h(acc);
    }
}

// ---------------- conv0: embed + LN0 (halo inline) + dw + pw + residual + LN1 ----------------
__global__ void conv0f(const float* __restrict__ in, const float* __restrict__ pe,
                       const float* __restrict__ g0, const float* __restrict__ b0,
                       float* __restrict__ xout, us* __restrict__ lnout,
                       const float* __restrict__ dwW, const float* __restrict__ dwB,
                       const us* __restrict__ pwW, const float* __restrict__ pwb,
                       const float* __restrict__ gnext, const float* __restrict__ bnext) {
    __shared__ us lnb_s[70 * 104];
    __shared__ us dwb_s[64 * 104];
    __shared__ float lw[96 * 8];
    int tid = threadIdx.x;
    int wave = tid >> 6, lane = tid & 63;
    int r0 = blockIdx.x * 64;
    int b = r0 / S, s0 = r0 % S;

    for (int i = tid; i < 96 * KW; i += 256) lw[(i / KW) * 8 + (i % KW)] = dwW[i];

    for (int i = wave; i < 70; i += 4) {
        int s = s0 - 3 + i;
        bool valid = (unsigned)s < (unsigned)S;
        float v0 = 0.f, v1 = 0.f;
        if (valid) {
            size_t ro = ((size_t)b * S + s) * 96;
            v0 = in[ro + lane] * SQRTD + pe[s * 96 + lane];
            v1 = (lane < 32) ? in[ro + 64 + lane] * SQRTD + pe[s * 96 + 64 + lane] : 0.f;
        }
        float sm = v0 + v1, q = v0 * v0 + v1 * v1;
        for (int off = 32; off > 0; off >>= 1) {
            sm += __shfl_xor(sm, off);
            q += __shfl_xor(q, off);
        }
        float mean = sm * (1.0f / D);
        float var = q * (1.0f / D) - mean * mean;
        float rstd = rsqrtf(var + 1e-5f);
        lnb_s[i * 104 + lane] = f2h(valid ? (v0 - mean) * rstd * g0[lane] + b0[lane] : 0.f);
        if (lane < 32)
            lnb_s[i * 104 + 64 + lane] =
                f2h(valid ? (v1 - mean) * rstd * g0[lane + 64] + b0[lane + 64] : 0.f);
    }
    __syncthreads();

    for (int u = tid; u < 768; u += 256) {
        int j = u / 12, c0 = (u - (u / 12) * 12) * 8;
        float acc[8];
        #pragma unroll
        for (int j2 = 0; j2 < 8; j2++) acc[j2] = dwB[c0 + j2];
        #pragma unroll
        for (int k = 0; k < KW; k++) {
            f16x8 v = ldh(&lnb_s[(j + k) * 104 + c0]);
            #pragma unroll
            for (int j2 = 0; j2 < 8; j2++) acc[j2] += (float)v[j2] * lw[(c0 + j2) * 8 + k];
        }
        us8 o;
        #pragma unroll
        for (int j2 = 0; j2 < 8; j2++) o[j2] = f2h(acc[j2]);
        *reinterpret_cast<us8*>(&dwb_s[j * 104 + c0]) = o;
    }
    __syncthreads();

    int lmod = lane & 15, ldiv = lane >> 4, m0 = wave * 16;
    f32x4 acc[6] = {};
    #pragma unroll
    for (int kk = 0; kk < 3; kk++) {
        f16x8 af = ldh(&dwb_s[(m0 + lmod) * 104 + kk * 32 + ldiv * 8]);
        #pragma unroll
        for (int n = 0; n < 6; n++) {
            f16x8 bf = ldh(pwW + (size_t)((n * 3 + kk) * 64) * 8 + lane * 8);
            acc[n] = __builtin_amdgcn_mfma_f32_16x16x32_f16(af, bf, acc[n], 0, 0, 0);
        }
    }

    float gv[6], bv2[6], pb[6];
    #pragma unroll
    for (int n = 0; n < 6; n++) {
        int o = n * 16 + lmod;
        gv[n] = gnext[o];
        bv2[n] = bnext[o];
        pb[n] = pwb[o];
    }
    #pragma unroll
    for (int n = 0; n < 6; n++) {
        int o = n * 16 + lmod;
        #pragma unroll
        for (int r = 0; r < 4; r++) {
            int sr = m0 + ldiv * 4 + r;
            size_t row = (size_t)r0 + sr;
            float base = in[row * 96 + o] * SQRTD + pe[(s0 + sr) * 96 + o];
            acc[n][r] = base + fmaxf(acc[n][r] + pb[n], 0.f);
        }
    }
    #pragma unroll
    for (int r = 0; r < 4; r++) {
        float sm = 0.f, qq = 0.f;
        #pragma unroll
        for (int n = 0; n < 6; n++) {
            sm += acc[n][r];
            qq += acc[n][r] * acc[n][r];
        }
        #pragma unroll
        for (int st = 1; st <= 8; st <<= 1) {
            sm += __shfl_xor(sm, st);
            qq += __shfl_xor(qq, st);
        }
        float mean = sm * (1.0f / D);
        float var = qq * (1.0f / D) - mean * mean;
        float rstd = rsqrtf(var + 1e-5f);
        size_t row = (size_t)r0 + m0 + ldiv * 4 + r;
        #pragma unroll
        for (int n = 0; n < 6; n++) {
            int o = n * 16 + lmod;
            xout[row * 96 + o] = acc[n][r];
            lnout[row * 96 + o] = f2h((acc[n][r] - mean) * rstd * gv[n] + bv2[n]);
        }
    }
}

// ---------------- mid conv layer ----------------
__global__ void conv2(const float* __restrict__ xin, const us* __restrict__ lnin,
                      float* __restrict__ xout, us* __restrict__ lnout,
                      const float* __restrict__ dwW, const float* __restrict__ dwB,
                      const us* __restrict__ pwW, const float* __restrict__ pwb,
                      const float* __restrict__ gnext, const float* __restrict__ bnext) {
    __shared__ us dwb_s[64 * 104];
    __shared__ float lw[96 * 8];
    int tid = threadIdx.x;
    int wave = tid >> 6, lane = tid & 63;
    int r0 = blockIdx.x * 64;
    int b = r0 / S, s0 = r0 % S;

    for (int i = tid; i < 96 * KW; i += 256) lw[(i / KW) * 8 + (i % KW)] = dwW[i];
    __syncthreads();

    for (int u = tid; u < 768; u += 256) {
        int j = u / 12, c0 = (u - (u / 12) * 12) * 8;
        float acc[8];
        #pragma unroll
        for (int j2 = 0; j2 < 8; j2++) acc[j2] = dwB[c0 + j2];
        #pragma unroll
        for (int k = 0; k < KW; k++) {
            int ss = s0 + j + k - 3;
            if ((unsigned)ss < (unsigned)S) {
                f16x8 v = ldh(lnin + ((size_t)b * S + ss) * 96 + c0);
                #pragma unroll
                for (int j2 = 0; j2 < 8; j2++) acc[j2] += (float)v[j2] * lw[(c0 + j2) * 8 + k];
            }
        }
        us8 o;
        #pragma unroll
        for (int j2 = 0; j2 < 8; j2++) o[j2] = f2h(acc[j2]);
        *reinterpret_cast<us8*>(&dwb_s[j * 104 + c0]) = o;
    }
    __syncthreads();

    int lmod = lane & 15, ldiv = lane >> 4, m0 = wave * 16;
    f32x4 acc[6] = {};
    #pragma unroll
    for (int kk = 0; kk < 3; kk++) {
        f16x8 af = ldh(&dwb_s[(m0 + lmod) * 104 + kk * 32 + ldiv * 8]);
        #pragma unroll
        for (int n = 0; n < 6; n++) {
            f16x8 bf = ldh(pwW + (size_t)((n * 3 + kk) * 64) * 8 + lane * 8);
            acc[n] = __builtin_amdgcn_mfma_f32_16x16x32_f16(af, bf, acc[n], 0, 0, 0);
        }
    }

    float gv[6], bv2[6], pb[6];
    #pragma unroll
    for (int n = 0; n < 6; n++) {
        int o = n * 16 + lmod;
        gv[n] = gnext[o];
        bv2[n] = bnext[o];
        pb[n] = pwb[o];
    }
    #pragma unroll
    for (int n = 0; n < 6; n++) {
        #pragma unroll
        for (int r = 0; r < 4; r++) {
            size_t row = (size_t)r0 + m0 + ldiv * 4 + r;
            acc[n][r] = xin[row * 96 + n * 16 + lmod] + fmaxf(acc[n][r] + pb[n], 0.f);
        }
    }
    #pragma unroll
    for (int r = 0; r < 4; r++) {
        float sm = 0.f, qq = 0.f;
        #pragma unroll
        for (int n = 0; n < 6; n++) {
            sm += acc[n][r];
            qq += acc[n][r] * acc[n][r];
        }
        #pragma unroll
        for (int st = 1; st <= 8; st <<= 1) {
            sm += __shfl_xor(sm, st);
            qq += __shfl_xor(qq, st);
        }
        float mean = sm * (1.0f / D);
        float var = qq * (1.0f / D) - mean * mean;
        float rstd = rsqrtf(var + 1e-5f);
        size_t row = (size_t)r0 + m0 + ldiv * 4 + r;
        #pragma unroll
        for (int n = 0; n < 6; n++) {
            int o = n * 16 + lmod;
            xout[row * 96 + o] = acc[n][r];
            lnout[row * 96 + o] = f2h((acc[n][r] - mean) * rstd * gv[n] + bv2[n]);
        }
    }
}

// ---------------- conv3 + K/V' projection fused (V 64-key-chunk layout) ----------------
__global__ void conv3p(const float* __restrict__ xin, const us* __restrict__ lnin,
                       float* __restrict__ xout, us* __restrict__ lnout,
                       const float* __restrict__ dwW, const float* __restrict__ dwB,
                       const us* __restrict__ pwW, const float* __restrict__ pwb,
                       const float* __restrict__ gnext, const float* __restrict__ bnext,
                       const us* __restrict__ wkS, const us* __restrict__ wvoS,
                       us* __restrict__ Kall, us* __restrict__ Vall) {
    __shared__ float lw[96 * 8];
    __shared__ us stg[96 * 72];
    __shared__ us lnstg[64 * 104];
    int tid = threadIdx.x;
    int wave = tid >> 6, lane = tid & 63;
    int lmod = lane & 15, ldiv = lane >> 4, m0 = wave * 16;
    int r0 = blockIdx.x * 64;
    int b = r0 / S, s0 = r0 % S;

    for (int i = tid; i < 96 * KW; i += 256) lw[(i / KW) * 8 + (i % KW)] = dwW[i];
    __syncthreads();

    for (int u = tid; u < 768; u += 256) {
        int j = u / 12, c0 = (u - (u / 12) * 12) * 8;
        float acc[8];
        #pragma unroll
        for (int j2 = 0; j2 < 8; j2++) acc[j2] = dwB[c0 + j2];
        #pragma unroll
        for (int k = 0; k < KW; k++) {
            int ss = s0 + j + k - 3;
            if ((unsigned)ss < (unsigned)S) {
                f16x8 v = ldh(lnin + ((size_t)b * S + ss) * 96 + c0);
                #pragma unroll
                for (int j2 = 0; j2 < 8; j2++) acc[j2] += (float)v[j2] * lw[(c0 + j2) * 8 + k];
            }
        }
        us8 o;
        #pragma unroll
        for (int j2 = 0; j2 < 8; j2++) o[j2] = f2h(acc[j2]);
        *reinterpret_cast<us8*>(&stg[j * 104 + c0]) = o;
    }
    __syncthreads();

    f32x4 acc[6] = {};
    #pragma unroll
    for (int kk = 0; kk < 3; kk++) {
        f16x8 af = ldh(&stg[(m0 + lmod) * 104 + kk * 32 + ldiv * 8]);
        #pragma unroll
        for (int n = 0; n < 6; n++) {
            f16x8 bf = ldh(pwW + (size_t)((n * 3 + kk) * 64) * 8 + lane * 8);
            acc[n] = __builtin_amdgcn_mfma_f32_16x16x32_f16(af, bf, acc[n], 0, 0, 0);
        }
    }

    float gv[6], bv2[6], pb[6];
    #pragma unroll
    for (int n = 0; n < 6; n++) {
        int o = n * 16 + lmod;
        gv[n] = gnext[o];
        bv2[n] = bnext[o];
        pb[n] = pwb[o];
    }
    #pragma unroll
    for (int n = 0; n < 6; n++) {
        #pragma unroll
        for (int r = 0; r < 4; r++) {
            size_t row = (size_t)r0 + m0 + ldiv * 4 + r;
            acc[n][r] = xin[row * 96 + n * 16 + lmod] + fmaxf(acc[n][r] + pb[n], 0.f);
        }
    }
    #pragma unroll
    for (int r = 0; r < 4; r++) {
        float sm = 0.f, qq = 0.f;
        #pragma unroll
        for (int n = 0; n < 6; n++) {
            sm += acc[n][r];
            qq += acc[n][r] * acc[n][r];
        }
        #pragma unroll
        for (int st = 1; st <= 8; st <<= 1) {
            sm += __shfl_xor(sm, st);
            qq += __shfl_xor(qq, st);
        }
        float mean = sm * (1.0f / D);
        float var = qq * (1.0f / D) - mean * mean;
        float rstd = rsqrtf(var + 1e-5f);
        size_t row = (size_t)r0 + m0 + ldiv * 4 + r;
        #pragma unroll
        for (int n = 0; n < 6; n++) {
            int o = n * 16 + lmod;
            xout[row * 96 + o] = acc[n][r];
            us hv = f2h((acc[n][r] - mean) * rstd * gv[n] + bv2[n]);
            lnout[row * 96 + o] = hv;
            lnstg[(m0 + ldiv * 4 + r) * 104 + o] = hv;
        }
    }
    __syncthreads();

    f16x8 af[3];
    #pragma unroll
    for (int kk = 0; kk < 3; kk++)
        af[kk] = ldh(&lnstg[(m0 + lmod) * 104 + kk * 32 + ldiv * 8]);

    for (int hd = 0; hd < H; hd++) {
        // ---- K ----
        f32x4 ka[6] = {};
        #pragma unroll
        for (int kk = 0; kk < 3; kk++)
            #pragma unroll
            for (int n = 0; n < 6; n++) {
                f16x8 bf = ldh(wkS + (size_t)hd * D * D + (size_t)((n * 3 + kk) * 64) * 8 + lane * 8);
                ka[n] = __builtin_amdgcn_mfma_f32_16x16x32_f16(af[kk], bf, ka[n], 0, 0, 0);
            }
        __syncthreads();
        us* kT = stg + wave * 1664;
        #pragma unroll
        for (int n = 0; n < 6; n++)
            #pragma unroll
            for (int r = 0; r < 4; r++)
                kT[(ldiv * 4 + r) * 104 + n * 16 + lmod] = f2h(ka[n][r]);
        int t0 = (r0 % S) / 16 + wave;
        us* dst = Kall + (size_t)hd * NTOT + ((size_t)(b * 24 + t0) * 3) * 512;
        #pragma unroll
        for (int kk = 0; kk < 3; kk++) {
            us8 v = *reinterpret_cast<const us8*>(&kT[lmod * 104 + kk * 32 + ldiv * 8]);
            *reinterpret_cast<us8*>(dst + kk * 512 + lane * 8) = v;
        }
        // ---- V' ---- 64-key-chunk layout: [b][cblk(6)][n(6)][kk(2)][512]
        f32x4 va[6] = {};
        #pragma unroll
        for (int kk = 0; kk < 3; kk++)
            #pragma unroll
            for (int n = 0; n < 6; n++) {
                f16x8 bf =
                    ldh(wvoS + (size_t)hd * D * D + (size_t)((n * 3 + kk) * 64) * 8 + lane * 8);
                va[n] = __builtin_amdgcn_mfma_f32_16x16x32_f16(af[kk], bf, va[n], 0, 0, 0);
            }
        __syncthreads();
        #pragma unroll
        for (int n = 0; n < 6; n++)
            #pragma unroll
            for (int r = 0; r < 4; r++)
                stg[(n * 16 + lmod) * 72 + m0 + ldiv * 4 + r] = f2h(va[n][r]);
        __syncthreads();
        int cblk = (r0 % S) / 64;
        us* dsth = Vall + (size_t)hd * NTOT;
        #pragma unroll
        for (int n = 0; n < 6; n++)
            #pragma unroll
            for (int kk = 0; kk < 2; kk++) {
                us8 v =
                    *reinterpret_cast<const us8*>(&stg[(n * 16 + lmod) * 72 + kk * 32 + ldiv * 8]);
                *reinterpret_cast<us8*>(
                    dsth + ((size_t)((b * 6 + cblk) * 6 + n) * 2 + kk) * 512 + lane * 8) = v;
            }
    }
}

// ---------------- one-pass online-softmax attention, swapped QK^T ----------------
// grid 1024 = 128 b x 4 hd x 2 qhalf; 4 waves x 48 q-rows; 64-key chunks, K/V dbuf.
__global__ __launch_bounds__(256, 2) void attn_g(const us* __restrict__ h16,
                                                 const us* __restrict__ wqS,
                                                 const us* __restrict__ Kall,
                                                 const us* __restrict__ Vall,
                                                 us* __restrict__ xpart) {
    __shared__ us pool[38400];  // Kb:0/6144 | Vb:12288/18432 | P:24576+wave*3456 ; prologue Qstage: wave*4992
    int tid = threadIdx.x, wave = tid >> 6, lane = tid & 63;
    int lmod = lane & 15, ldiv = lane >> 4;
    int p = blockIdx.x;
    int gl = (p & 7) * 128 + (p >> 3);  // XCD swizzle, 1024 = 8*128
    int qt = gl & 1;
    int bh = gl >> 1;
    int b = bh >> 2, hd = bh & 3;
    size_t rowbase = (size_t)b * S + qt * 192 + wave * 48;

    const us* Kh = Kall + (size_t)hd * NTOT + (size_t)b * 24 * 1536;
    const us* Vh = Vall + (size_t)hd * NTOT + (size_t)b * 36 * 1024;
    us* P = pool + 24576 + wave * 3456;  // [48][72]

    // prologue: issue K0 + V0 staging loads; Q-proj under their latency
    us8 k0s[3], v0s[3];
    #pragma unroll
    for (int j = 0; j < 3; j++) {
        k0s[j] = *reinterpret_cast<const us8*>(Kh + (size_t)(j * 256 + tid) * 8);
        v0s[j] = *reinterpret_cast<const us8*>(Vh + (size_t)(j * 256 + tid) * 8);
    }

    f32x4 qa0[6] = {}, qa1[6] = {}, qa2[6] = {};
    #pragma unroll
    for (int kk = 0; kk < 3; kk++) {
        f16x8 a0 = ldh(h16 + (rowbase + lmod) * 96 + kk * 32 + ldiv * 8);
        f16x8 a1 = ldh(h16 + (rowbase + 16 + lmod) * 96 + kk * 32 + ldiv * 8);
        f16x8 a2 = ldh(h16 + (rowbase + 32 + lmod) * 96 + kk * 32 + ldiv * 8);
        #pragma unroll
        for (int n = 0; n < 6; n++) {
            f16x8 bf = ldh(wqS + (size_t)hd * D * D + (size_t)((n * 3 + kk) * 64) * 8 + lane * 8);
            qa0[n] = __builtin_amdgcn_mfma_f32_16x16x32_f16(a0, bf, qa0[n], 0, 0, 0);
            qa1[n] = __builtin_amdgcn_mfma_f32_16x16x32_f16(a1, bf, qa1[n], 0, 0, 0);
            qa2[n] = __builtin_amdgcn_mfma_f32_16x16x32_f16(a2, bf, qa2[n], 0, 0, 0);
        }
    }
    us* qst = pool + wave * 4992;  // [48][104], wave-private (overlaps Kb/Vb; barrier below)
    #pragma unroll
    for (int n = 0; n < 6; n++)
        #pragma unroll
        for (int r = 0; r < 4; r++) {
            qst[(ldiv * 4 + r) * 104 + n * 16 + lmod] = f2h(qa0[n][r]);
            qst[(16 + ldiv * 4 + r) * 104 + n * 16 + lmod] = f2h(qa1[n][r]);
            qst[(32 + ldiv * 4 + r) * 104 + n * 16 + lmod] = f2h(qa2[n][r]);
        }
    f16x8 aq0[3], aq1[3], aq2[3];
    #pragma unroll
    for (int kk = 0; kk < 3; kk++) {
        aq0[kk] = ldh(&qst[lmod * 104 + kk * 32 + ldiv * 8]);
        aq1[kk] = ldh(&qst[(16 + lmod) * 104 + kk * 32 + ldiv * 8]);
        aq2[kk] = ldh(&qst[(32 + lmod) * 104 + kk * 32 + ldiv * 8]);
    }
    __syncthreads();  // all waves done with Q staging in pool
    #pragma unroll
    for (int j = 0; j < 3; j++) {
        *reinterpret_cast<us8*>(&pool[(j * 256 + tid) * 8]) = k0s[j];
        *reinterpret_cast<us8*>(&pool[12288 + (j * 256 + tid) * 8]) = v0s[j];
    }
    __syncthreads();

    // ---- single pass: scores (swapped) -> online softmax -> PV ----
    float m0v = -1e30f, m1v = -1e30f, m2v = -1e30f;
    float l0 = 0.f, l1 = 0.f, l2 = 0.f;
    f32x4 oacc0[6] = {}, oacc1[6] = {}, oacc2[6] = {};
    for (int c = 0; c < 6; c++) {
        us* kbc = pool + (c & 1) * 6144;
        us* vbc = pool + 12288 + (c & 1) * 6144;
        us8 kn[3], vn[3];
        if (c < 5) {
            const us* ksrc = Kh + (size_t)(c + 1) * 6144;
            const us* vsrc = Vh + (size_t)(c + 1) * 6144;
            #pragma unroll
            for (int j = 0; j < 3; j++) {
                kn[j] = *reinterpret_cast<const us8*>(ksrc + (size_t)(j * 256 + tid) * 8);
                vn[j] = *reinterpret_cast<const us8*>(vsrc + (size_t)(j * 256 + tid) * 8);
            }
        }
        __builtin_amdgcn_s_setprio(1);
        f32x4 s0[4] = {}, s1[4] = {}, s2[4] = {};
        #pragma unroll
        for (int nt = 0; nt < 4; nt++)
            #pragma unroll
            for (int kk = 0; kk < 3; kk++) {
                f16x8 bf = ldh(&kbc[(nt * 3 + kk) * 512 + lane * 8]);
                s0[nt] = __builtin_amdgcn_mfma_f32_16x16x32_f16(bf, aq0[kk], s0[nt], 0, 0, 0);
                s1[nt] = __builtin_amdgcn_mfma_f32_16x16x32_f16(bf, aq1[kk], s1[nt], 0, 0, 0);
                s2[nt] = __builtin_amdgcn_mfma_f32_16x16x32_f16(bf, aq2[kk], s2[nt], 0, 0, 0);
            }
        __builtin_amdgcn_s_setprio(0);
        // online max update (m per lane, row q = lmod; uniform across ldiv groups)
        float cm0 = -1e30f, cm1 = -1e30f, cm2 = -1e30f;
        #pragma unroll
        for (int nt = 0; nt < 4; nt++)
            #pragma unroll
            for (int r = 0; r < 4; r++) {
                cm0 = fmaxf(cm0, s0[nt][r]);
                cm1 = fmaxf(cm1, s1[nt][r]);
                cm2 = fmaxf(cm2, s2[nt][r]);
            }
        cm0 = fmaxf(cm0, __shfl_xor(cm0, 16));
        cm0 = fmaxf(cm0, __shfl_xor(cm0, 32));
        cm1 = fmaxf(cm1, __shfl_xor(cm1, 16));
        cm1 = fmaxf(cm1, __shfl_xor(cm1, 32));
        cm2 = fmaxf(cm2, __shfl_xor(cm2, 16));
        cm2 = fmaxf(cm2, __shfl_xor(cm2, 32));
        float mn0 = fmaxf(m0v, cm0), mn1 = fmaxf(m1v, cm1), mn2 = fmaxf(m2v, cm2);
        float sc0 = exp2f(m0v - mn0), sc1 = exp2f(m1v - mn1), sc2 = exp2f(m2v - mn2);
        m0v = mn0;
        m1v = mn1;
        m2v = mn2;
        l0 *= sc0;
        l1 *= sc1;
        l2 *= sc2;
        #pragma unroll
        for (int r = 0; r < 4; r++) {
            int srcl = ldiv * 4 + r;
            float s0r = __shfl(sc0, srcl);
            float s1r = __shfl(sc1, srcl);
            float s2r = __shfl(sc2, srcl);
            #pragma unroll
            for (int n = 0; n < 6; n++) {
                oacc0[n][r] *= s0r;
                oacc1[n][r] *= s1r;
                oacc2[n][r] *= s2r;
            }
        }
        // exp2 + packed b64 P writes (row = t*16+lmod, k = nt*16+ldiv*4+r)
        #pragma unroll
        for (int nt = 0; nt < 4; nt++) {
            us4 pk0, pk1, pk2;
            #pragma unroll
            for (int r = 0; r < 4; r++) {
                float p0 = exp2f(s0[nt][r] - m0v);
                float p1 = exp2f(s1[nt][r] - m1v);
                float p2 = exp2f(s2[nt][r] - m2v);
                l0 += p0;
                l1 += p1;
                l2 += p2;
                pk0[r] = f2h(p0);
                pk1[r] = f2h(p1);
                pk2[r] = f2h(p2);
            }
            int kc = nt * 16 + ldiv * 4;
            *reinterpret_cast<us4*>(&P[lmod * 72 + kc]) = pk0;
            *reinterpret_cast<us4*>(&P[(16 + lmod) * 72 + kc]) = pk1;
            *reinterpret_cast<us4*>(&P[(32 + lmod) * 72 + kc]) = pk2;
        }
        __builtin_amdgcn_s_setprio(1);
        #pragma unroll
        for (int kk = 0; kk < 2; kk++) {
            f16x8 pf0 = ldh(&P[lmod * 72 + kk * 32 + ldiv * 8]);
            f16x8 pf1 = ldh(&P[(16 + lmod) * 72 + kk * 32 + ldiv * 8]);
            f16x8 pf2 = ldh(&P[(32 + lmod) * 72 + kk * 32 + ldiv * 8]);
            #pragma unroll
            for (int n = 0; n < 6; n++) {
                f16x8 bf = ldh(&vbc[(n * 2 + kk) * 512 + lane * 8]);
                oacc0[n] = __builtin_amdgcn_mfma_f32_16x16x32_f16(pf0, bf, oacc0[n], 0, 0, 0);
                oacc1[n] = __builtin_amdgcn_mfma_f32_16x16x32_f16(pf1, bf, oacc1[n], 0, 0, 0);
                oacc2[n] = __builtin_amdgcn_mfma_f32_16x16x32_f16(pf2, bf, oacc2[n], 0, 0, 0);
            }
        }
        __builtin_amdgcn_s_setprio(0);
        if (c < 5) {
            us* kbn = pool + ((c & 1) ^ 1) * 6144;
            us* vbn = pool + 12288 + ((c & 1) ^ 1) * 6144;
            #pragma unroll
            for (int j = 0; j < 3; j++) {
                *reinterpret_cast<us8*>(&kbn[(j * 256 + tid) * 8]) = kn[j];
                *reinterpret_cast<us8*>(&vbn[(j * 256 + tid) * 8]) = vn[j];
            }
            __syncthreads();
        }
    }
    l0 += __shfl_xor(l0, 16);
    l0 += __shfl_xor(l0, 32);
    l1 += __shfl_xor(l1, 16);
    l1 += __shfl_xor(l1, 32);
    l2 += __shfl_xor(l2, 16);
    l2 += __shfl_xor(l2, 32);

    // epilogue: l lives at lane lmod=q; oacc rows are q=ldiv*4+r -> shuffle redistribute
    us* xp = xpart + (size_t)hd * NTOT;
    #pragma unroll
    for (int r = 0; r < 4; r++) {
        int srcl = ldiv * 4 + r;  // lane < 16 has lmod == srcl
        float inv0 = 1.f / __shfl(l0, srcl);
        float inv1 = 1.f / __shfl(l1, srcl);
        float inv2 = 1.f / __shfl(l2, srcl);
        #pragma unroll
        for (int n = 0; n < 6; n++) {
            xp[(rowbase + ldiv * 4 + r) * 96 + n * 16 + lmod] = f2h(oacc0[n][r] * inv0);
            xp[(rowbase + 16 + ldiv * 4 + r) * 96 + n * 16 + lmod] = f2h(oacc1[n][r] * inv1);
            xp[(rowbase + 32 + ldiv * 4 + r) * 96 + n * 16 + lmod] = f2h(oacc2[n][r] * inv2);
        }
    }
}

// ---------------- fused head-reduce + LN + FFN ----------------
__global__ void ffn_ln(const float* __restrict__ x, const us* __restrict__ xpart,
                       const float* __restrict__ gln, const float* __restrict__ bln,
                       const us* __restrict__ w1S, const float* __restrict__ b1,
                       const us* __restrict__ w2S, const float* __restrict__ b2,
                       float* __restrict__ out) {
    __shared__ float xf[64 * 96];
    __shared__ us lnb[64 * 104];
    __shared__ us mid[64 * 72];
    int tid = threadIdx.x, wave = tid >> 6, lane = tid & 63;
    int lmod = lane & 15, ldiv = lane >> 4, m0 = wave * 16;
    int row0 = blockIdx.x * 64;

    for (int i = wave; i < 64; i += 4) {
        size_t ro = (size_t)(row0 + i) * 96;
        float v0 = x[ro + lane];
        float v1 = (lane < 32) ? x[ro + 64 + lane] : 0.f;
        #pragma unroll
        for (int h = 0; h < H; h++) {
            const us* xp = xpart + (size_t)h * NTOT + ro;
            v0 += (float)__builtin_bit_cast(_Float16, xp[lane]);
            if (lane < 32) v1 += (float)__builtin_bit_cast(_Float16, xp[64 + lane]);
        }
        xf[i * 96 + lane] = v0;
        if (lane < 32) xf[i * 96 + 64 + lane] = v1;
        float sm = v0 + v1, q = v0 * v0 + v1 * v1;
        for (int off = 32; off > 0; off >>= 1) {
            sm += __shfl_xor(sm, off);
            q += __shfl_xor(q, off);
        }
        float mean = sm * (1.0f / D);
        float var = q * (1.0f / D) - mean * mean;
        float rstd = rsqrtf(var + 1e-5f);
        lnb[i * 104 + lane] = f2h((v0 - mean) * rstd * gln[lane] + bln[lane]);
        if (lane < 32)
            lnb[i * 104 + 64 + lane] = f2h((v1 - mean) * rstd * gln[lane + 64] + bln[lane + 64]);
    }
    __syncthreads();

    f32x4 a3[3] = {};
    #pragma unroll
    for (int kk = 0; kk < 3; kk++) {
        f16x8 af = ldh(&lnb[(m0 + lmod) * 104 + kk * 32 + ldiv * 8]);
        #pragma unroll
        for (int n = 0; n < 3; n++) {
            f16x8 bf = ldh(w1S + (size_t)((n * 3 + kk) * 64) * 8 + lane * 8);
            a3[n] = __builtin_amdgcn_mfma_f32_16x16x32_f16(af, bf, a3[n], 0, 0, 0);
        }
    }
    #pragma unroll
    for (int n = 0; n < 3; n++) {
        float bv = b1[n * 16 + lmod];
        #pragma unroll
        for (int r = 0; r < 4; r++) {
            float v = a3[n][r] + bv;
            mid[(m0 + ldiv * 4 + r) * 72 + n * 16 + lmod] = f2h(1.f / (1.f + __expf(-v)));
        }
    }
    #pragma unroll
    for (int r = 0; r < 4; r++) mid[(m0 + ldiv * 4 + r) * 72 + 48 + lmod] = 0;
    __syncthreads();

    f32x4 a6[6] = {};
    #pragma unroll
    for (int kk = 0; kk < 2; kk++) {
        f16x8 af = ldh(&mid[(m0 + lmod) * 72 + kk * 32 + ldiv * 8]);
        #pragma unroll
        for (int n = 0; n < 6; n++) {
            f16x8 bf = ldh(w2S + (size_t)((n * 2 + kk) * 64) * 8 + lane * 8);
            a6[n] = __builtin_amdgcn_mfma_f32_16x16x32_f16(af, bf, a6[n], 0, 0, 0);
        }
    }
    #pragma unroll
    for (int n = 0; n < 6; n++) {
        int o = n * 16 + lmod;
        float bv = b2[o];
        #pragma unroll
        for (int r = 0; r < 4; r++) {
            int sr = m0 + ldiv * 4 + r;
            out[(size_t)(row0 + sr) * 96 + o] = xf[sr * 96 + o] + a6[n][r] + bv;
        }
    }
}

extern "C" void kernel_launch(void* const* d_in, const int* in_sizes, int n_in,
                              void* d_out, int out_size, void* d_ws, size_t ws_size,
                              hipStream_t stream) {
    const float* in   = (const float*)d_in[0];
    const float* cdw  = (const float*)d_in[2];
    const float* cdwb = (const float*)d_in[3];
    const float* cpw  = (const float*)d_in[4];
    const float* cpwb = (const float*)d_in[5];
    const float* WQ   = (const float*)d_in[6];
    const float* WK   = (const float*)d_in[7];
    const float* WV   = (const float*)d_in[8];
    const float* WO   = (const float*)d_in[9];
    const float* w1   = (const float*)d_in[10];
    const float* b1   = (const float*)d_in[11];
    const float* w2   = (const float*)d_in[12];
    const float* b2   = (const float*)d_in[13];
    const float* lng  = (const float*)d_in[14];
    const float* lnb  = (const float*)d_in[15];
    float* out = (float*)d_out;
    float* ws = (float*)d_ws;

    float* xA  = ws;
    float* xB  = xA + NTOT;
    float* pe  = xB + NTOT;
    us* lnA    = (us*)(pe + S * D);
    us* lnB    = lnA + NTOT;
    us* Kall   = lnB + NTOT;               // [H][B][24][3][64][8]
    us* Vall   = Kall + (size_t)H * NTOT;  // [H][B][6 cblk][6 n][2 kk][512]
    us* xpart  = Vall + (size_t)H * NTOT;  // [H][ROWS][96]
    us* wqS    = xpart + (size_t)H * NTOT;
    us* wkS    = wqS + H * D * D;
    us* wvoS   = wkS + H * D * D;
    us* pwS    = wvoS + H * D * D;
    us* w1S    = pwS + L * D * D;
    us* w2S    = w1S + 48 * 96;
    // total ~= 170 MB (< 256 MB ws)

    pe_kernel<<<(S * D + 255) / 256, 256, 0, stream>>>(pe);
    prep_w<<<(H * D * D + 255) / 256, 256, 0, stream>>>(WQ, WK, cpw, w1, w2,
                                                        wqS, wkS, pwS, w1S, w2S);
    prep_wvo<<<H * 6, 256, 0, stream>>>(WV, WO, wvoS);

    conv0f<<<ROWS / 64, 256, 0, stream>>>(in, pe, lng, lnb, xA, lnB,
                                          cdw, cdwb, pwS, cpwb, lng + D, lnb + D);
    conv2<<<ROWS / 64, 256, 0, stream>>>(xA, lnB, xB, lnA, cdw + D * KW, cdwb + D,
                                         pwS + D * D, cpwb + D, lng + 2 * D, lnb + 2 * D);
    conv2<<<ROWS / 64, 256, 0, stream>>>(xB, lnA, xA, lnB, cdw + 2 * D * KW, cdwb + 2 * D,
                                         pwS + 2 * D * D, cpwb + 2 * D, lng + 3 * D,
                                         lnb + 3 * D);
    conv3p<<<ROWS / 64, 256, 0, stream>>>(xA, lnB, xB, lnA, cdw + 3 * D * KW, cdwb + 3 * D,
                                          pwS + 3 * D * D, cpwb + 3 * D, lng + 4 * D,
                                          lnb + 4 * D, wkS, wvoS, Kall, Vall);

    // lnA == h16, xB == x4
    attn_g<<<1024, 256, 0, stream>>>(lnA, wqS, Kall, Vall, xpart);

    ffn_ln<<<ROWS / 64, 256, 0, stream>>>(xB, xpart, lng + 5 * D, lnb + 5 * D,
                                          w1S, b1, w2S, b2, out);
}